// Round 6
// baseline (595.739 us; speedup 1.0000x reference)
//
#include <hip/hip_runtime.h>

#define BATCH 16384
#define DIM   4096

typedef __bf16 bf16x8 __attribute__((ext_vector_type(8)));
typedef float  f32x4  __attribute__((ext_vector_type(4)));
typedef unsigned short u16x8 __attribute__((ext_vector_type(8)));
typedef unsigned short u16x4 __attribute__((ext_vector_type(4)));

// ---- workspace layout (float offsets) ----
#define WS_ROWSUM 0         // 16384
#define WS_MED    16384     // 1
#define WS_NPART  16400     // 512*2
#define WS_SC3    17536     // 64
#define WS_CC3    17600     // 64
#define WS_A2PART 18432     // 256*64
#define WS_A3PART 34816     // 256*128
#define WS_CPART  67584     // 512*128 (per-block col sum[64] then sumsq[64])
#define WS_R      133120    // 16384*64 fp32
#define WS_A2     1181696   // 16384*32 fp32
#define WS_A3     1705984   // 16384*64 fp32
#define WS_WTIN   2754560   // 64*4096 bf16 (as ushort)
#define WS_WTO    2885632   // 3 * 4096*64 bf16

__device__ __forceinline__ unsigned short f2bf(float f){
  union { float f; unsigned u; } v; v.f = f;
  unsigned r = v.u + 0x7FFFu + ((v.u >> 16) & 1u);
  return (unsigned short)(r >> 16);
}

// L0: weight transpose/bf16 prep via LDS (blocks 0..255, coalesced 128B+ writes)
//     + row sums of x (blocks 256..4351).
__global__ __launch_bounds__(256) void k_prep_rowsum(
    const float* __restrict__ x, const float* __restrict__ Win,
    const float* __restrict__ Wpi, const float* __restrict__ Wm,
    const float* __restrict__ Wth, float* __restrict__ ws){
  int b = blockIdx.x, t = threadIdx.x;
  if (b < 256) {
    __shared__ unsigned short tile[64][72];   // 72 -> 144B row stride (16B aligned)
    if (b < 64) {
      int k0 = b * 64;
      int n = t & 63, kb = t >> 6;
      #pragma unroll
      for (int i = 0; i < 16; ++i) {
        int kk = kb * 16 + i;
        tile[n][kk] = f2bf(Win[(size_t)(k0 + kk) * 64 + n]);
      }
      __syncthreads();
      unsigned short* wtin = (unsigned short*)(ws + WS_WTIN);
      int c = t & 7;
      #pragma unroll
      for (int p = 0; p < 2; ++p) {
        int nn = (t >> 3) + p * 32;
        u16x8 v = *(const u16x8*)&tile[nn][c * 8];
        *(u16x8*)(wtin + (size_t)nn * 4096 + k0 + c * 8) = v;
      }
    } else {
      int bm = (b - 64) >> 6;
      int n0 = ((b - 64) & 63) * 64;
      const float* W = (bm == 0) ? Wpi : ((bm == 1) ? Wm : Wth);
      int nn = t & 63, kb = t >> 6;
      #pragma unroll
      for (int i = 0; i < 16; ++i) {
        int k = kb * 16 + i;
        tile[nn][k] = f2bf(W[(size_t)k * 4096 + n0 + nn]);
      }
      __syncthreads();
      unsigned short* wto = (unsigned short*)(ws + WS_WTO);
      int c = t & 7;
      #pragma unroll
      for (int p = 0; p < 2; ++p) {
        int nn2 = (t >> 3) + p * 32;
        u16x8 v = *(const u16x8*)&tile[nn2][c * 8];
        *(u16x8*)(wto + (size_t)bm * 262144 + (size_t)(n0 + nn2) * 64 + c * 8) = v;
      }
    }
  } else {
    int w = t >> 6, lane = t & 63;
    int row = (b - 256) * 4 + w;
    const float4* xr = (const float4*)(x + (size_t)row * DIM);
    float s = 0.f;
    #pragma unroll
    for (int i = 0; i < 16; ++i) {
      float4 v = xr[lane + 64 * i];
      s += (v.x + v.y) + (v.z + v.w);
    }
    #pragma unroll
    for (int m = 32; m; m >>= 1) s += __shfl_xor(s, m);
    if (lane == 0) ws[WS_ROWSUM + row] = s;
  }
}

// L1: exact lower median of 16384 positive floats via 3-pass MSD radix (bits 12/12/8).
__global__ __launch_bounds__(1024) void k_median(float* __restrict__ ws){
  __shared__ unsigned keys[16384];
  __shared__ int hist[4096];
  __shared__ int scanbuf[1024];
  __shared__ int selBin, selRank;
  int t = threadIdx.x, lane = t & 63;

  for (int i = t; i < 16384; i += 1024) keys[i] = __float_as_uint(ws[WS_ROWSUM + i]);
  for (int i = t; i < 4096; i += 1024) hist[i] = 0;
  __syncthreads();

  auto scanFind = [&](int target) {
    int s = hist[4*t] + hist[4*t+1] + hist[4*t+2] + hist[4*t+3];
    scanbuf[t] = s;
    __syncthreads();
    for (int off = 1; off < 1024; off <<= 1) {
      int v = scanbuf[t];
      int a = (t >= off) ? scanbuf[t - off] : 0;
      __syncthreads();
      scanbuf[t] = v + a;
      __syncthreads();
    }
    int acc = scanbuf[t] - s;
    #pragma unroll
    for (int j = 0; j < 4; ++j) {
      int c = hist[4*t + j];
      if (acc <= target && target < acc + c) { selBin = 4*t + j; selRank = target - acc; }
      acc += c;
    }
    __syncthreads();
  };

  for (int i = t; i < 16384; i += 1024) {
    unsigned key = keys[i] >> 20;
    unsigned long long unclaimed = __ballot(1);
    int cnt = 0; bool leader = false;
    while (true) {
      int src = (int)(__ffsll((unsigned long long)unclaimed)) - 1;
      unsigned k0 = (unsigned)__shfl((int)key, src);
      unsigned long long eq = __ballot(k0 == key);
      if (k0 == key) { leader = (lane == src); cnt = (int)__popcll(eq); break; }
      unclaimed &= ~eq;
    }
    if (leader) atomicAdd(&hist[key], cnt);
  }
  __syncthreads();
  scanFind(8191);
  unsigned B1 = (unsigned)selBin; int r1 = selRank;
  __syncthreads();
  for (int i = t; i < 4096; i += 1024) hist[i] = 0;
  __syncthreads();
  for (int i = t; i < 16384; i += 1024) {
    unsigned u = keys[i];
    if ((u >> 20) == B1) atomicAdd(&hist[(u >> 8) & 0xFFF], 1);
  }
  __syncthreads();
  scanFind(r1);
  unsigned B2 = (unsigned)selBin; int r2 = selRank;
  __syncthreads();
  for (int i = t; i < 4096; i += 1024) hist[i] = 0;
  __syncthreads();
  unsigned hi24 = (B1 << 12) | B2;
  for (int i = t; i < 16384; i += 1024) {
    unsigned u = keys[i];
    if ((u >> 8) == hi24) atomicAdd(&hist[u & 0xFF], 1);
  }
  __syncthreads();
  scanFind(r2);
  if (t == 0) {
    unsigned bits = (B1 << 20) | (B2 << 8) | (unsigned)selBin;
    ws[WS_MED] = __uint_as_float(bits);
  }
}

// L2: fused norm + R = norm @ W_in, per-block column sum/sumsq of R, global norm stats.
// BM=32 rows, grid 512, ONE barrier per K-step, FOUR-deep register prefetch
// (tile j <-> register set j&3; load issued 2 phases before its LDS stage).
__global__ __launch_bounds__(512) void k_passB(const float* __restrict__ x, float* __restrict__ ws){
  __shared__ __align__(16) char Ab[2 * 4096];
  __shared__ __align__(16) char Bb[2 * 8192];
  __shared__ float ainv_s[32];
  __shared__ float redn[8][2];
  __shared__ float cpart[2][64], cqpart[2][64];

  const unsigned short* wtin = (const unsigned short*)(ws + WS_WTIN);
  int tid = threadIdx.x;
  int r0 = blockIdx.x * 32;
  float med = ws[WS_MED];
  if (tid < 32) ainv_s[tid] = med / ws[WS_ROWSUM + r0 + tid];
  __syncthreads();

  int w = tid >> 6, lane = tid & 63;
  int li = lane & 15, u = lane >> 4;
  int wrb = (w & 1) * 16;
  int wc  = (w >> 1) * 16;

  int xrow = tid >> 4;
  int xcol0 = (tid & 15) * 4;
  int wn = tid >> 3, wkc = tid & 7;
  float ainv = ainv_s[xrow];

  f32x4 acc = (f32x4){0.f, 0.f, 0.f, 0.f};
  float nsum = 0.f, nsq = 0.f;
  float4 xa0, xa1, xa2, xa3; u16x8 wv0, wv1, wv2, wv3;

  auto LOADT = [&](int tt, float4& xv, u16x8& wq){
    int coff = tt * 64;
    xv = *(const float4*)(x + (size_t)(r0 + xrow) * DIM + coff + xcol0);
    wq = *(const u16x8*)(wtin + (size_t)wn * DIM + coff + wkc * 8);
  };
  auto WRITET = [&](int buf, const float4& xv, const u16x8& wq){
    float n0 = __logf(fmaf(xv.x, ainv, 1.f));
    float n1 = __logf(fmaf(xv.y, ainv, 1.f));
    float n2 = __logf(fmaf(xv.z, ainv, 1.f));
    float n3 = __logf(fmaf(xv.w, ainv, 1.f));
    nsum += (n0 + n1) + (n2 + n3);
    nsq  += (n0*n0 + n1*n1) + (n2*n2 + n3*n3);
    u16x4 p = { f2bf(n0), f2bf(n1), f2bf(n2), f2bf(n3) };
    int c = xcol0 >> 3, sub = (xcol0 >> 2) & 1;
    *(u16x4*)(Ab + buf * 4096 + xrow * 128 + ((c ^ (xrow & 7)) << 4) + sub * 8) = p;
    *(u16x8*)(Bb + buf * 8192 + wn * 128 + ((wkc ^ (wn & 7)) << 4)) = wq;
  };
  int arow = wrb + li, brow = wc + li;
  auto DOMFMA = [&](int p){
    const char* Au = Ab + p * 4096;
    const char* Bu = Bb + p * 8192;
    #pragma unroll
    for (int kk = 0; kk < 2; ++kk) {
      bf16x8 aF = *(const bf16x8*)(Au + arow * 128 + (((kk * 4 + u) ^ (arow & 7)) << 4));
      bf16x8 bF = *(const bf16x8*)(Bu + brow * 128 + (((kk * 4 + u) ^ (brow & 7)) << 4));
      acc = __builtin_amdgcn_mfma_f32_16x16x32_bf16(bF, aF, acc, 0, 0, 0);
    }
  };

  // preamble: tiles 0,1,2 in sets s0,s1,s2; tile 0 staged to buf0.
  LOADT(0, xa0, wv0);
  LOADT(1, xa1, wv1);
  LOADT(2, xa2, wv2);
  WRITET(0, xa0, wv0);
  __syncthreads();
  for (int t = 0; t < 64; t += 4) {
    // P0: compute buf0=tile t; stage tile t+1 (s1->buf1); load tile t+3 -> s3
    if (t + 3 < 64) LOADT(t + 3, xa3, wv3);
    WRITET(1, xa1, wv1);
    DOMFMA(0);
    __syncthreads();
    // P1: compute buf1=tile t+1; stage tile t+2 (s2->buf0); load tile t+4 -> s0
    if (t + 4 < 64) LOADT(t + 4, xa0, wv0);
    WRITET(0, xa2, wv2);
    DOMFMA(1);
    __syncthreads();
    // P2: compute buf0=tile t+2; stage tile t+3 (s3->buf1); load tile t+5 -> s1
    if (t + 5 < 64) LOADT(t + 5, xa1, wv1);
    if (t + 3 < 64) WRITET(1, xa3, wv3);
    DOMFMA(0);
    __syncthreads();
    // P3: compute buf1=tile t+3; stage tile t+4 (s0->buf0); load tile t+6 -> s2
    if (t + 6 < 64) LOADT(t + 6, xa2, wv2);
    if (t + 4 < 64) WRITET(0, xa0, wv0);
    DOMFMA(1);
    __syncthreads();
  }

  float* R = ws + WS_R;
  *(f32x4*)(R + (size_t)(r0 + wrb + li) * 64 + wc + u * 4) = acc;

  float s0 = acc[0], s1 = acc[1], s2 = acc[2], s3 = acc[3];
  float q0 = acc[0]*acc[0], q1 = acc[1]*acc[1], q2 = acc[2]*acc[2], q3 = acc[3]*acc[3];
  #pragma unroll
  for (int m = 1; m < 16; m <<= 1) {
    s0 += __shfl_xor(s0, m); s1 += __shfl_xor(s1, m);
    s2 += __shfl_xor(s2, m); s3 += __shfl_xor(s3, m);
    q0 += __shfl_xor(q0, m); q1 += __shfl_xor(q1, m);
    q2 += __shfl_xor(q2, m); q3 += __shfl_xor(q3, m);
  }
  if (li == 0) {
    int cb = wc + u * 4;
    cpart[w & 1][cb + 0] = s0; cpart[w & 1][cb + 1] = s1;
    cpart[w & 1][cb + 2] = s2; cpart[w & 1][cb + 3] = s3;
    cqpart[w & 1][cb + 0] = q0; cqpart[w & 1][cb + 1] = q1;
    cqpart[w & 1][cb + 2] = q2; cqpart[w & 1][cb + 3] = q3;
  }
  #pragma unroll
  for (int m = 32; m; m >>= 1) { nsum += __shfl_xor(nsum, m); nsq += __shfl_xor(nsq, m); }
  if (lane == 0) { redn[w][0] = nsum; redn[w][1] = nsq; }
  __syncthreads();
  if (tid < 64) {
    ws[WS_CPART + blockIdx.x * 128 + tid]      = cpart[0][tid] + cpart[1][tid];
    ws[WS_CPART + blockIdx.x * 128 + 64 + tid] = cqpart[0][tid] + cqpart[1][tid];
  }
  if (tid == 0) {
    float S = 0.f, Q = 0.f;
    for (int i = 0; i < 8; ++i) { S += redn[i][0]; Q += redn[i][1]; }
    ws[WS_NPART + blockIdx.x * 2]     = S;
    ws[WS_NPART + blockIdx.x * 2 + 1] = Q;
  }
}

// L3: BN1 finalize + h1 = relu(BN1(R)), a2 = h1 @ W_enc + b_enc, a2 partials.
__global__ __launch_bounds__(256) void k_layer1(const float* __restrict__ g1, const float* __restrict__ bt1,
                         const float* __restrict__ Wenc, const float* __restrict__ benc,
                         float* __restrict__ ws){
  __shared__ float sc1[64], cc1[64];
  __shared__ float h1[64][65];
  __shared__ float we[64][33];
  __shared__ float sred[4][64], qred[4][64];
  __shared__ float sigred[4][2];
  __shared__ float sig2s;
  int t = threadIdx.x, lane = t & 63, w4 = t >> 6;

  {
    float s = 0.f, q = 0.f;
    for (int b = t; b < 512; b += 256) { s += ws[WS_NPART + b * 2]; q += ws[WS_NPART + b * 2 + 1]; }
    #pragma unroll
    for (int m = 32; m; m >>= 1) { s += __shfl_xor(s, m); q += __shfl_xor(q, m); }
    if (lane == 0) { sigred[w4][0] = s; sigred[w4][1] = q; }
  }
  {
    int col = t & 63, grp = t >> 6;
    float S = 0.f, Q = 0.f;
    for (int b = grp * 128; b < grp * 128 + 128; ++b) {
      S += ws[WS_CPART + b * 128 + col];
      Q += ws[WS_CPART + b * 128 + 64 + col];
    }
    sred[grp][col] = S; qred[grp][col] = Q;
  }
  for (int i = t; i < 2048; i += 256) we[i >> 5][i & 31] = Wenc[i];
  __syncthreads();
  if (t == 0) {
    double Sn = (double)sigred[0][0] + sigred[1][0] + sigred[2][0] + sigred[3][0];
    double Qn = (double)sigred[0][1] + sigred[1][1] + sigred[2][1] + sigred[3][1];
    double N = 67108864.0;
    sig2s = (float)((Qn - Sn * Sn / N) / (N - 1.0));
  }
  __syncthreads();
  if (t < 64) {
    float Sc = sred[0][t] + sred[1][t] + sred[2][t] + sred[3][t];
    float Qc = qred[0][t] + qred[1][t] + qred[2][t] + qred[3][t];
    float cm = Sc * (1.f / 16384.f);
    float cv = Qc * (1.f / 16384.f) - cm * cm;
    float sc = g1[t] * rsqrtf(cv + sig2s * 1e-5f);
    sc1[t] = sc; cc1[t] = bt1[t] - cm * sc;
  }
  __syncthreads();

  int r0 = blockIdx.x * 64;
  const float* R = ws + WS_R;
  for (int i = t; i < 4096; i += 256) {
    int row = i >> 6, col = i & 63;
    float v = fmaf(R[(size_t)(r0 + row) * 64 + col], sc1[col], cc1[col]);
    h1[row][col] = fmaxf(v, 0.f);
  }
  __syncthreads();
  int row = t & 63, cb = t >> 6;
  float a[8];
  #pragma unroll
  for (int j = 0; j < 8; ++j) a[j] = benc[cb * 8 + j];
  for (int k = 0; k < 64; ++k) {
    float hv = h1[row][k];
    #pragma unroll
    for (int j = 0; j < 8; ++j) a[j] = fmaf(hv, we[k][cb * 8 + j], a[j]);
  }
  float* A2 = ws + WS_A2;
  #pragma unroll
  for (int j = 0; j < 8; ++j) A2[(size_t)(r0 + row) * 32 + cb * 8 + j] = a[j];
  #pragma unroll
  for (int j = 0; j < 8; ++j) {
    float s = a[j], q = a[j] * a[j];
    #pragma unroll
    for (int m = 32; m; m >>= 1) { s += __shfl_xor(s, m); q += __shfl_xor(q, m); }
    if (lane == 0) {
      int c = cb * 8 + j;
      ws[WS_A2PART + blockIdx.x * 64 + c * 2]     = s;
      ws[WS_A2PART + blockIdx.x * 64 + c * 2 + 1] = q;
    }
  }
}

// L4: BN2 finalize + h2 = relu(BN2(a2)), a3 = h2 @ W_dec + b_dec, a3 partials.
__global__ __launch_bounds__(256) void k_layer2(const float* __restrict__ g2, const float* __restrict__ bt2,
                         const float* __restrict__ Wdec, const float* __restrict__ bdec,
                         float* __restrict__ ws){
  __shared__ float h2[64][33];
  __shared__ float wd[32][65];
  __shared__ float sc2[32], cc2[32];
  __shared__ float sred2[8][32], qred2[8][32];
  int t = threadIdx.x, lane = t & 63;
  {
    int col = t & 31, grp = t >> 5;
    float S = 0.f, Q = 0.f;
    for (int b = grp * 32; b < grp * 32 + 32; ++b) {
      S += ws[WS_A2PART + b * 64 + col * 2];
      Q += ws[WS_A2PART + b * 64 + col * 2 + 1];
    }
    sred2[grp][col] = S; qred2[grp][col] = Q;
  }
  for (int i = t; i < 2048; i += 256) wd[i >> 6][i & 63] = Wdec[i];
  __syncthreads();
  if (t < 32) {
    float Sc = 0.f, Qc = 0.f;
    #pragma unroll
    for (int g = 0; g < 8; ++g) { Sc += sred2[g][t]; Qc += qred2[g][t]; }
    float cm = Sc * (1.f / 16384.f);
    float cv = Qc * (1.f / 16384.f) - cm * cm;
    float sc = g2[t] * rsqrtf(cv + 1e-5f);
    sc2[t] = sc; cc2[t] = bt2[t] - cm * sc;
  }
  __syncthreads();
  int r0 = blockIdx.x * 64;
  const float* A2 = ws + WS_A2;
  for (int i = t; i < 2048; i += 256) {
    int row = i >> 5, col = i & 31;
    float v = fmaf(A2[(size_t)(r0 + row) * 32 + col], sc2[col], cc2[col]);
    h2[row][col] = fmaxf(v, 0.f);
  }
  __syncthreads();
  int row = t & 63, cb = t >> 6;
  float a[16];
  #pragma unroll
  for (int j = 0; j < 16; ++j) a[j] = bdec[cb * 16 + j];
  for (int k = 0; k < 32; ++k) {
    float hv = h2[row][k];
    #pragma unroll
    for (int j = 0; j < 16; ++j) a[j] = fmaf(hv, wd[k][cb * 16 + j], a[j]);
  }
  float* A3 = ws + WS_A3;
  #pragma unroll
  for (int j = 0; j < 16; ++j) A3[(size_t)(r0 + row) * 64 + cb * 16 + j] = a[j];
  #pragma unroll
  for (int j = 0; j < 16; ++j) {
    float s = a[j], q = a[j] * a[j];
    #pragma unroll
    for (int m = 32; m; m >>= 1) { s += __shfl_xor(s, m); q += __shfl_xor(q, m); }
    if (lane == 0) {
      int c = cb * 16 + j;
      ws[WS_A3PART + blockIdx.x * 128 + c * 2]     = s;
      ws[WS_A3PART + blockIdx.x * 128 + c * 2 + 1] = q;
    }
  }
}

// L5: reduce a3 partials -> BN3 scale/shift.
__global__ void k_red3(const float* __restrict__ g3, const float* __restrict__ bt3, float* __restrict__ ws){
  __shared__ float red[128];
  int t = threadIdx.x;
  if (t < 128) {
    float s = 0.f;
    for (int b = 0; b < 256; ++b) s += ws[WS_A3PART + b * 128 + t];
    red[t] = s;
  }
  __syncthreads();
  if (t < 64) {
    float S = red[2 * t], Q = red[2 * t + 1];
    float cm = S * (1.f / 16384.f);
    float cv = Q * (1.f / 16384.f) - cm * cm;
    float sc = g3[t] * rsqrtf(cv + 1e-5f);
    ws[WS_SC3 + t] = sc; ws[WS_CC3 + t] = bt3[t] - cm * sc;
  }
}

// L6: heads. h3 = relu(BN3(a3)) in-register; out = act(h3 @ W + b).
// LDS-FREE: B-fragments read directly from wto global (L2-resident, exact MFMA
// layout: 16B/lane at n*64 + u*8). No barriers, no LDS occupancy cap.
__global__ __launch_bounds__(256) void k_out(const float* __restrict__ bpi, const float* __restrict__ bm,
                      const float* __restrict__ bth, float* __restrict__ out,
                      float* __restrict__ ws){
  int t = threadIdx.x;
  int bx = blockIdx.x;
  int rb = bx >> 4, cb = bx & 15;
  int r0 = rb * 64, c0 = cb * 256;
  int w = t >> 6, lane = t & 63;
  int u = lane >> 4, li = lane & 15;

  const float* A3 = ws + WS_A3;
  const float* SC = ws + WS_SC3;
  const float* CC = ws + WS_CC3;
  int arow = r0 + w * 16 + li;
  const float4* a3p = (const float4*)(A3 + (size_t)arow * 64);
  bf16x8 aF[2];
  #pragma unroll
  for (int h = 0; h < 2; ++h) {
    float4 v0 = a3p[h * 8 + u * 2];
    float4 v1 = a3p[h * 8 + u * 2 + 1];
    int kb = h * 32 + u * 8;
    u16x8 uu;
    uu[0] = f2bf(fmaxf(fmaf(v0.x, SC[kb+0], CC[kb+0]), 0.f));
    uu[1] = f2bf(fmaxf(fmaf(v0.y, SC[kb+1], CC[kb+1]), 0.f));
    uu[2] = f2bf(fmaxf(fmaf(v0.z, SC[kb+2], CC[kb+2]), 0.f));
    uu[3] = f2bf(fmaxf(fmaf(v0.w, SC[kb+3], CC[kb+3]), 0.f));
    uu[4] = f2bf(fmaxf(fmaf(v1.x, SC[kb+4], CC[kb+4]), 0.f));
    uu[5] = f2bf(fmaxf(fmaf(v1.y, SC[kb+5], CC[kb+5]), 0.f));
    uu[6] = f2bf(fmaxf(fmaf(v1.z, SC[kb+6], CC[kb+6]), 0.f));
    uu[7] = f2bf(fmaxf(fmaf(v1.w, SC[kb+7], CC[kb+7]), 0.f));
    aF[h] = __builtin_bit_cast(bf16x8, uu);
  }

  const unsigned short* wto = (const unsigned short*)(ws + WS_WTO);
  for (int m = 0; m < 3; ++m) {
    const unsigned short* src = wto + (size_t)m * 262144 + (size_t)c0 * 64;
    const float* bias = (m == 0) ? bpi : ((m == 1) ? bm : bth);
    float* po = out + (size_t)m * 67108864;
    for (int cg = 0; cg < 16; ++cg) {
      int n = cg * 16 + li;
      bf16x8 bF0 = *(const bf16x8*)(src + (size_t)n * 64 + u * 8);
      bf16x8 bF1 = *(const bf16x8*)(src + (size_t)n * 64 + 32 + u * 8);
      f32x4 d = (f32x4){0.f, 0.f, 0.f, 0.f};
      d = __builtin_amdgcn_mfma_f32_16x16x32_bf16(bF0, aF[0], d, 0, 0, 0);
      d = __builtin_amdgcn_mfma_f32_16x16x32_bf16(bF1, aF[1], d, 0, 0, 0);
      int colb = c0 + cg * 16 + u * 4;
      f32x4 bv = *(const f32x4*)(bias + colb);
      f32x4 z;
      #pragma unroll
      for (int r = 0; r < 4; ++r) {
        float zz = d[r] + bv[r];
        z[r] = (m == 0) ? (1.f / (1.f + __expf(-zz))) : __expf(zz);
      }
      *(f32x4*)(po + (size_t)arow * 4096 + colb) = z;
    }
  }
}

extern "C" void kernel_launch(void* const* d_in, const int* in_sizes, int n_in,
                              void* d_out, int out_size, void* d_ws, size_t ws_size,
                              hipStream_t stream) {
  const float* x    = (const float*)d_in[0];
  const float* Win  = (const float*)d_in[1];
  // d_in[2] = b_in: cancels through BN1, unused.
  const float* g1   = (const float*)d_in[3];
  const float* bt1  = (const float*)d_in[4];
  const float* Wenc = (const float*)d_in[5];
  const float* benc = (const float*)d_in[6];
  const float* g2   = (const float*)d_in[7];
  const float* bt2  = (const float*)d_in[8];
  const float* Wdec = (const float*)d_in[9];
  const float* bdec = (const float*)d_in[10];
  const float* g3   = (const float*)d_in[11];
  const float* bt3  = (const float*)d_in[12];
  const float* Wpi  = (const float*)d_in[13];
  const float* bpi  = (const float*)d_in[14];
  const float* Wm   = (const float*)d_in[15];
  const float* bm   = (const float*)d_in[16];
  const float* Wth  = (const float*)d_in[17];
  const float* bth  = (const float*)d_in[18];
  float* ws  = (float*)d_ws;
  float* out = (float*)d_out;

  hipLaunchKernelGGL(k_prep_rowsum, dim3(4352), dim3(256),  0, stream, x, Win, Wpi, Wm, Wth, ws);
  hipLaunchKernelGGL(k_median,      dim3(1),    dim3(1024), 0, stream, ws);
  hipLaunchKernelGGL(k_passB,       dim3(512),  dim3(512),  0, stream, x, ws);
  hipLaunchKernelGGL(k_layer1,      dim3(256),  dim3(256),  0, stream, g1, bt1, Wenc, benc, ws);
  hipLaunchKernelGGL(k_layer2,      dim3(256),  dim3(256),  0, stream, g2, bt2, Wdec, bdec, ws);
  hipLaunchKernelGGL(k_red3,        dim3(1),    dim3(256),  0, stream, g3, bt3, ws);
  hipLaunchKernelGGL(k_out,         dim3(4096), dim3(256),  0, stream, bpi, bm, bth, out, ws);
}

// Round 7
// 431.460 us; speedup vs baseline: 1.3808x; 1.3808x over previous
//
#include <hip/hip_runtime.h>

#define BATCH 16384
#define DIM   4096

typedef __bf16 bf16x8 __attribute__((ext_vector_type(8)));
typedef float  f32x4  __attribute__((ext_vector_type(4)));
typedef unsigned short u16x8 __attribute__((ext_vector_type(8)));
typedef unsigned short u16x4 __attribute__((ext_vector_type(4)));

// ---- workspace layout (float offsets) ----
#define WS_ROWSUM 0         // 16384
#define WS_MED    16384     // 1
#define WS_NPART  16400     // 512*2
#define WS_SC3    17536     // 64
#define WS_CC3    17600     // 64
#define WS_A2PART 18432     // 256*64
#define WS_A3PART 34816     // 256*128
#define WS_CPART  67584     // 512*128 (per-block col sum[64] then sumsq[64])
#define WS_R      133120    // 16384*64 fp32
#define WS_A2     1181696   // 16384*32 fp32
#define WS_A3     1705984   // 16384*64 fp32
#define WS_WTIN   2754560   // 64*4096 bf16 (as ushort)
#define WS_WTO    2885632   // 3 * 4096*64 bf16

__device__ __forceinline__ unsigned short f2bf(float f){
  union { float f; unsigned u; } v; v.f = f;
  unsigned r = v.u + 0x7FFFu + ((v.u >> 16) & 1u);
  return (unsigned short)(r >> 16);
}

// L0: weight transpose/bf16 prep via LDS (blocks 0..255, coalesced 128B+ writes)
//     + row sums of x (blocks 256..4351).
__global__ __launch_bounds__(256) void k_prep_rowsum(
    const float* __restrict__ x, const float* __restrict__ Win,
    const float* __restrict__ Wpi, const float* __restrict__ Wm,
    const float* __restrict__ Wth, float* __restrict__ ws){
  int b = blockIdx.x, t = threadIdx.x;
  if (b < 256) {
    __shared__ unsigned short tile[64][72];   // 72 -> 144B row stride (16B aligned)
    if (b < 64) {
      int k0 = b * 64;
      int n = t & 63, kb = t >> 6;
      #pragma unroll
      for (int i = 0; i < 16; ++i) {
        int kk = kb * 16 + i;
        tile[n][kk] = f2bf(Win[(size_t)(k0 + kk) * 64 + n]);
      }
      __syncthreads();
      unsigned short* wtin = (unsigned short*)(ws + WS_WTIN);
      int c = t & 7;
      #pragma unroll
      for (int p = 0; p < 2; ++p) {
        int nn = (t >> 3) + p * 32;
        u16x8 v = *(const u16x8*)&tile[nn][c * 8];
        *(u16x8*)(wtin + (size_t)nn * 4096 + k0 + c * 8) = v;
      }
    } else {
      int bm = (b - 64) >> 6;
      int n0 = ((b - 64) & 63) * 64;
      const float* W = (bm == 0) ? Wpi : ((bm == 1) ? Wm : Wth);
      int nn = t & 63, kb = t >> 6;
      #pragma unroll
      for (int i = 0; i < 16; ++i) {
        int k = kb * 16 + i;
        tile[nn][k] = f2bf(W[(size_t)k * 4096 + n0 + nn]);
      }
      __syncthreads();
      unsigned short* wto = (unsigned short*)(ws + WS_WTO);
      int c = t & 7;
      #pragma unroll
      for (int p = 0; p < 2; ++p) {
        int nn2 = (t >> 3) + p * 32;
        u16x8 v = *(const u16x8*)&tile[nn2][c * 8];
        *(u16x8*)(wto + (size_t)bm * 262144 + (size_t)(n0 + nn2) * 64 + c * 8) = v;
      }
    }
  } else {
    int w = t >> 6, lane = t & 63;
    int row = (b - 256) * 4 + w;
    const float4* xr = (const float4*)(x + (size_t)row * DIM);
    float s = 0.f;
    #pragma unroll
    for (int i = 0; i < 16; ++i) {
      float4 v = xr[lane + 64 * i];
      s += (v.x + v.y) + (v.z + v.w);
    }
    #pragma unroll
    for (int m = 32; m; m >>= 1) s += __shfl_xor(s, m);
    if (lane == 0) ws[WS_ROWSUM + row] = s;
  }
}

// L1: exact lower median of 16384 positive floats via 3-pass MSD radix (bits 12/12/8).
__global__ __launch_bounds__(1024) void k_median(float* __restrict__ ws){
  __shared__ unsigned keys[16384];
  __shared__ int hist[4096];
  __shared__ int scanbuf[1024];
  __shared__ int selBin, selRank;
  int t = threadIdx.x, lane = t & 63;

  for (int i = t; i < 16384; i += 1024) keys[i] = __float_as_uint(ws[WS_ROWSUM + i]);
  for (int i = t; i < 4096; i += 1024) hist[i] = 0;
  __syncthreads();

  auto scanFind = [&](int target) {
    int s = hist[4*t] + hist[4*t+1] + hist[4*t+2] + hist[4*t+3];
    scanbuf[t] = s;
    __syncthreads();
    for (int off = 1; off < 1024; off <<= 1) {
      int v = scanbuf[t];
      int a = (t >= off) ? scanbuf[t - off] : 0;
      __syncthreads();
      scanbuf[t] = v + a;
      __syncthreads();
    }
    int acc = scanbuf[t] - s;
    #pragma unroll
    for (int j = 0; j < 4; ++j) {
      int c = hist[4*t + j];
      if (acc <= target && target < acc + c) { selBin = 4*t + j; selRank = target - acc; }
      acc += c;
    }
    __syncthreads();
  };

  for (int i = t; i < 16384; i += 1024) {
    unsigned key = keys[i] >> 20;
    unsigned long long unclaimed = __ballot(1);
    int cnt = 0; bool leader = false;
    while (true) {
      int src = (int)(__ffsll((unsigned long long)unclaimed)) - 1;
      unsigned k0 = (unsigned)__shfl((int)key, src);
      unsigned long long eq = __ballot(k0 == key);
      if (k0 == key) { leader = (lane == src); cnt = (int)__popcll(eq); break; }
      unclaimed &= ~eq;
    }
    if (leader) atomicAdd(&hist[key], cnt);
  }
  __syncthreads();
  scanFind(8191);
  unsigned B1 = (unsigned)selBin; int r1 = selRank;
  __syncthreads();
  for (int i = t; i < 4096; i += 1024) hist[i] = 0;
  __syncthreads();
  for (int i = t; i < 16384; i += 1024) {
    unsigned u = keys[i];
    if ((u >> 20) == B1) atomicAdd(&hist[(u >> 8) & 0xFFF], 1);
  }
  __syncthreads();
  scanFind(r1);
  unsigned B2 = (unsigned)selBin; int r2 = selRank;
  __syncthreads();
  for (int i = t; i < 4096; i += 1024) hist[i] = 0;
  __syncthreads();
  unsigned hi24 = (B1 << 12) | B2;
  for (int i = t; i < 16384; i += 1024) {
    unsigned u = keys[i];
    if ((u >> 8) == hi24) atomicAdd(&hist[u & 0xFF], 1);
  }
  __syncthreads();
  scanFind(r2);
  if (t == 0) {
    unsigned bits = (B1 << 20) | (B2 << 8) | (unsigned)selBin;
    ws[WS_MED] = __uint_as_float(bits);
  }
}

// L2: fused norm + R = norm @ W_in, per-block column sum/sumsq of R, global norm stats.
// BM=32 rows, grid 512, ONE barrier per K-step, FOUR-deep register prefetch
// (tile j <-> register set j&3; load issued 2 phases before its LDS stage).
__global__ __launch_bounds__(512) void k_passB(const float* __restrict__ x, float* __restrict__ ws){
  __shared__ __align__(16) char Ab[2 * 4096];
  __shared__ __align__(16) char Bb[2 * 8192];
  __shared__ float ainv_s[32];
  __shared__ float redn[8][2];
  __shared__ float cpart[2][64], cqpart[2][64];

  const unsigned short* wtin = (const unsigned short*)(ws + WS_WTIN);
  int tid = threadIdx.x;
  int r0 = blockIdx.x * 32;
  float med = ws[WS_MED];
  if (tid < 32) ainv_s[tid] = med / ws[WS_ROWSUM + r0 + tid];
  __syncthreads();

  int w = tid >> 6, lane = tid & 63;
  int li = lane & 15, u = lane >> 4;
  int wrb = (w & 1) * 16;
  int wc  = (w >> 1) * 16;

  int xrow = tid >> 4;
  int xcol0 = (tid & 15) * 4;
  int wn = tid >> 3, wkc = tid & 7;
  float ainv = ainv_s[xrow];

  f32x4 acc = (f32x4){0.f, 0.f, 0.f, 0.f};
  float nsum = 0.f, nsq = 0.f;
  float4 xa0, xa1, xa2, xa3; u16x8 wv0, wv1, wv2, wv3;

  auto LOADT = [&](int tt, float4& xv, u16x8& wq){
    int coff = tt * 64;
    xv = *(const float4*)(x + (size_t)(r0 + xrow) * DIM + coff + xcol0);
    wq = *(const u16x8*)(wtin + (size_t)wn * DIM + coff + wkc * 8);
  };
  auto WRITET = [&](int buf, const float4& xv, const u16x8& wq){
    float n0 = __logf(fmaf(xv.x, ainv, 1.f));
    float n1 = __logf(fmaf(xv.y, ainv, 1.f));
    float n2 = __logf(fmaf(xv.z, ainv, 1.f));
    float n3 = __logf(fmaf(xv.w, ainv, 1.f));
    nsum += (n0 + n1) + (n2 + n3);
    nsq  += (n0*n0 + n1*n1) + (n2*n2 + n3*n3);
    u16x4 p = { f2bf(n0), f2bf(n1), f2bf(n2), f2bf(n3) };
    int c = xcol0 >> 3, sub = (xcol0 >> 2) & 1;
    *(u16x4*)(Ab + buf * 4096 + xrow * 128 + ((c ^ (xrow & 7)) << 4) + sub * 8) = p;
    *(u16x8*)(Bb + buf * 8192 + wn * 128 + ((wkc ^ (wn & 7)) << 4)) = wq;
  };
  int arow = wrb + li, brow = wc + li;
  auto DOMFMA = [&](int p){
    const char* Au = Ab + p * 4096;
    const char* Bu = Bb + p * 8192;
    #pragma unroll
    for (int kk = 0; kk < 2; ++kk) {
      bf16x8 aF = *(const bf16x8*)(Au + arow * 128 + (((kk * 4 + u) ^ (arow & 7)) << 4));
      bf16x8 bF = *(const bf16x8*)(Bu + brow * 128 + (((kk * 4 + u) ^ (brow & 7)) << 4));
      acc = __builtin_amdgcn_mfma_f32_16x16x32_bf16(bF, aF, acc, 0, 0, 0);
    }
  };

  // preamble: tiles 0,1,2 in sets s0,s1,s2; tile 0 staged to buf0.
  LOADT(0, xa0, wv0);
  LOADT(1, xa1, wv1);
  LOADT(2, xa2, wv2);
  WRITET(0, xa0, wv0);
  __syncthreads();
  for (int t = 0; t < 64; t += 4) {
    // P0: compute buf0=tile t; stage tile t+1 (s1->buf1); load tile t+3 -> s3
    if (t + 3 < 64) LOADT(t + 3, xa3, wv3);
    WRITET(1, xa1, wv1);
    DOMFMA(0);
    __syncthreads();
    // P1: compute buf1=tile t+1; stage tile t+2 (s2->buf0); load tile t+4 -> s0
    if (t + 4 < 64) LOADT(t + 4, xa0, wv0);
    WRITET(0, xa2, wv2);
    DOMFMA(1);
    __syncthreads();
    // P2: compute buf0=tile t+2; stage tile t+3 (s3->buf1); load tile t+5 -> s1
    if (t + 5 < 64) LOADT(t + 5, xa1, wv1);
    if (t + 3 < 64) WRITET(1, xa3, wv3);
    DOMFMA(0);
    __syncthreads();
    // P3: compute buf1=tile t+3; stage tile t+4 (s0->buf0); load tile t+6 -> s2
    if (t + 6 < 64) LOADT(t + 6, xa2, wv2);
    if (t + 4 < 64) WRITET(0, xa0, wv0);
    DOMFMA(1);
    __syncthreads();
  }

  float* R = ws + WS_R;
  *(f32x4*)(R + (size_t)(r0 + wrb + li) * 64 + wc + u * 4) = acc;

  float s0 = acc[0], s1 = acc[1], s2 = acc[2], s3 = acc[3];
  float q0 = acc[0]*acc[0], q1 = acc[1]*acc[1], q2 = acc[2]*acc[2], q3 = acc[3]*acc[3];
  #pragma unroll
  for (int m = 1; m < 16; m <<= 1) {
    s0 += __shfl_xor(s0, m); s1 += __shfl_xor(s1, m);
    s2 += __shfl_xor(s2, m); s3 += __shfl_xor(s3, m);
    q0 += __shfl_xor(q0, m); q1 += __shfl_xor(q1, m);
    q2 += __shfl_xor(q2, m); q3 += __shfl_xor(q3, m);
  }
  if (li == 0) {
    int cb = wc + u * 4;
    cpart[w & 1][cb + 0] = s0; cpart[w & 1][cb + 1] = s1;
    cpart[w & 1][cb + 2] = s2; cpart[w & 1][cb + 3] = s3;
    cqpart[w & 1][cb + 0] = q0; cqpart[w & 1][cb + 1] = q1;
    cqpart[w & 1][cb + 2] = q2; cqpart[w & 1][cb + 3] = q3;
  }
  #pragma unroll
  for (int m = 32; m; m >>= 1) { nsum += __shfl_xor(nsum, m); nsq += __shfl_xor(nsq, m); }
  if (lane == 0) { redn[w][0] = nsum; redn[w][1] = nsq; }
  __syncthreads();
  if (tid < 64) {
    ws[WS_CPART + blockIdx.x * 128 + tid]      = cpart[0][tid] + cpart[1][tid];
    ws[WS_CPART + blockIdx.x * 128 + 64 + tid] = cqpart[0][tid] + cqpart[1][tid];
  }
  if (tid == 0) {
    float S = 0.f, Q = 0.f;
    for (int i = 0; i < 8; ++i) { S += redn[i][0]; Q += redn[i][1]; }
    ws[WS_NPART + blockIdx.x * 2]     = S;
    ws[WS_NPART + blockIdx.x * 2 + 1] = Q;
  }
}

// L3: BN1 finalize + h1 = relu(BN1(R)), a2 = h1 @ W_enc + b_enc, a2 partials.
__global__ __launch_bounds__(256) void k_layer1(const float* __restrict__ g1, const float* __restrict__ bt1,
                         const float* __restrict__ Wenc, const float* __restrict__ benc,
                         float* __restrict__ ws){
  __shared__ float sc1[64], cc1[64];
  __shared__ float h1[64][65];
  __shared__ float we[64][33];
  __shared__ float sred[4][64], qred[4][64];
  __shared__ float sigred[4][2];
  __shared__ float sig2s;
  int t = threadIdx.x, lane = t & 63, w4 = t >> 6;

  {
    float s = 0.f, q = 0.f;
    for (int b = t; b < 512; b += 256) { s += ws[WS_NPART + b * 2]; q += ws[WS_NPART + b * 2 + 1]; }
    #pragma unroll
    for (int m = 32; m; m >>= 1) { s += __shfl_xor(s, m); q += __shfl_xor(q, m); }
    if (lane == 0) { sigred[w4][0] = s; sigred[w4][1] = q; }
  }
  {
    int col = t & 63, grp = t >> 6;
    float S = 0.f, Q = 0.f;
    for (int b = grp * 128; b < grp * 128 + 128; ++b) {
      S += ws[WS_CPART + b * 128 + col];
      Q += ws[WS_CPART + b * 128 + 64 + col];
    }
    sred[grp][col] = S; qred[grp][col] = Q;
  }
  for (int i = t; i < 2048; i += 256) we[i >> 5][i & 31] = Wenc[i];
  __syncthreads();
  if (t == 0) {
    double Sn = (double)sigred[0][0] + sigred[1][0] + sigred[2][0] + sigred[3][0];
    double Qn = (double)sigred[0][1] + sigred[1][1] + sigred[2][1] + sigred[3][1];
    double N = 67108864.0;
    sig2s = (float)((Qn - Sn * Sn / N) / (N - 1.0));
  }
  __syncthreads();
  if (t < 64) {
    float Sc = sred[0][t] + sred[1][t] + sred[2][t] + sred[3][t];
    float Qc = qred[0][t] + qred[1][t] + qred[2][t] + qred[3][t];
    float cm = Sc * (1.f / 16384.f);
    float cv = Qc * (1.f / 16384.f) - cm * cm;
    float sc = g1[t] * rsqrtf(cv + sig2s * 1e-5f);
    sc1[t] = sc; cc1[t] = bt1[t] - cm * sc;
  }
  __syncthreads();

  int r0 = blockIdx.x * 64;
  const float* R = ws + WS_R;
  for (int i = t; i < 4096; i += 256) {
    int row = i >> 6, col = i & 63;
    float v = fmaf(R[(size_t)(r0 + row) * 64 + col], sc1[col], cc1[col]);
    h1[row][col] = fmaxf(v, 0.f);
  }
  __syncthreads();
  int row = t & 63, cb = t >> 6;
  float a[8];
  #pragma unroll
  for (int j = 0; j < 8; ++j) a[j] = benc[cb * 8 + j];
  for (int k = 0; k < 64; ++k) {
    float hv = h1[row][k];
    #pragma unroll
    for (int j = 0; j < 8; ++j) a[j] = fmaf(hv, we[k][cb * 8 + j], a[j]);
  }
  float* A2 = ws + WS_A2;
  #pragma unroll
  for (int j = 0; j < 8; ++j) A2[(size_t)(r0 + row) * 32 + cb * 8 + j] = a[j];
  #pragma unroll
  for (int j = 0; j < 8; ++j) {
    float s = a[j], q = a[j] * a[j];
    #pragma unroll
    for (int m = 32; m; m >>= 1) { s += __shfl_xor(s, m); q += __shfl_xor(q, m); }
    if (lane == 0) {
      int c = cb * 8 + j;
      ws[WS_A2PART + blockIdx.x * 64 + c * 2]     = s;
      ws[WS_A2PART + blockIdx.x * 64 + c * 2 + 1] = q;
    }
  }
}

// L4: BN2 finalize + h2 = relu(BN2(a2)), a3 = h2 @ W_dec + b_dec, a3 partials.
__global__ __launch_bounds__(256) void k_layer2(const float* __restrict__ g2, const float* __restrict__ bt2,
                         const float* __restrict__ Wdec, const float* __restrict__ bdec,
                         float* __restrict__ ws){
  __shared__ float h2[64][33];
  __shared__ float wd[32][65];
  __shared__ float sc2[32], cc2[32];
  __shared__ float sred2[8][32], qred2[8][32];
  int t = threadIdx.x, lane = t & 63;
  {
    int col = t & 31, grp = t >> 5;
    float S = 0.f, Q = 0.f;
    for (int b = grp * 32; b < grp * 32 + 32; ++b) {
      S += ws[WS_A2PART + b * 64 + col * 2];
      Q += ws[WS_A2PART + b * 64 + col * 2 + 1];
    }
    sred2[grp][col] = S; qred2[grp][col] = Q;
  }
  for (int i = t; i < 2048; i += 256) wd[i >> 6][i & 63] = Wdec[i];
  __syncthreads();
  if (t < 32) {
    float Sc = 0.f, Qc = 0.f;
    #pragma unroll
    for (int g = 0; g < 8; ++g) { Sc += sred2[g][t]; Qc += qred2[g][t]; }
    float cm = Sc * (1.f / 16384.f);
    float cv = Qc * (1.f / 16384.f) - cm * cm;
    float sc = g2[t] * rsqrtf(cv + 1e-5f);
    sc2[t] = sc; cc2[t] = bt2[t] - cm * sc;
  }
  __syncthreads();
  int r0 = blockIdx.x * 64;
  const float* A2 = ws + WS_A2;
  for (int i = t; i < 2048; i += 256) {
    int row = i >> 5, col = i & 31;
    float v = fmaf(A2[(size_t)(r0 + row) * 32 + col], sc2[col], cc2[col]);
    h2[row][col] = fmaxf(v, 0.f);
  }
  __syncthreads();
  int row = t & 63, cb = t >> 6;
  float a[16];
  #pragma unroll
  for (int j = 0; j < 16; ++j) a[j] = bdec[cb * 16 + j];
  for (int k = 0; k < 32; ++k) {
    float hv = h2[row][k];
    #pragma unroll
    for (int j = 0; j < 16; ++j) a[j] = fmaf(hv, wd[k][cb * 16 + j], a[j]);
  }
  float* A3 = ws + WS_A3;
  #pragma unroll
  for (int j = 0; j < 16; ++j) A3[(size_t)(r0 + row) * 64 + cb * 16 + j] = a[j];
  #pragma unroll
  for (int j = 0; j < 16; ++j) {
    float s = a[j], q = a[j] * a[j];
    #pragma unroll
    for (int m = 32; m; m >>= 1) { s += __shfl_xor(s, m); q += __shfl_xor(q, m); }
    if (lane == 0) {
      int c = cb * 16 + j;
      ws[WS_A3PART + blockIdx.x * 128 + c * 2]     = s;
      ws[WS_A3PART + blockIdx.x * 128 + c * 2 + 1] = q;
    }
  }
}

// L5: reduce a3 partials -> BN3 scale/shift.
__global__ void k_red3(const float* __restrict__ g3, const float* __restrict__ bt3, float* __restrict__ ws){
  __shared__ float red[128];
  int t = threadIdx.x;
  if (t < 128) {
    float s = 0.f;
    for (int b = 0; b < 256; ++b) s += ws[WS_A3PART + b * 128 + t];
    red[t] = s;
  }
  __syncthreads();
  if (t < 64) {
    float S = red[2 * t], Q = red[2 * t + 1];
    float cm = S * (1.f / 16384.f);
    float cv = Q * (1.f / 16384.f) - cm * cm;
    float sc = g3[t] * rsqrtf(cv + 1e-5f);
    ws[WS_SC3 + t] = sc; ws[WS_CC3 + t] = bt3[t] - cm * sc;
  }
}

// L6: heads. h3 = relu(BN3(a3)) in-register; out = act(h3 @ W + b).
// LDS-staged B (round-5 proven): stage 32KB tile once per head, share across waves.
__global__ __launch_bounds__(256) void k_out(const float* __restrict__ bpi, const float* __restrict__ bm,
                      const float* __restrict__ bth, float* __restrict__ out,
                      float* __restrict__ ws){
  __shared__ __align__(16) char WB[256 * 128];   // [256 n][64 k] bf16, XOR-swizzled
  int t = threadIdx.x;
  int bx = blockIdx.x;
  int rb = bx >> 4, cb = bx & 15;
  int r0 = rb * 64, c0 = cb * 256;
  int w = t >> 6, lane = t & 63;
  int u = lane >> 4, li = lane & 15;

  const float* A3 = ws + WS_A3;
  const float* SC = ws + WS_SC3;
  const float* CC = ws + WS_CC3;
  int arow = r0 + w * 16 + li;
  const float4* a3p = (const float4*)(A3 + (size_t)arow * 64);
  bf16x8 aF[2];
  #pragma unroll
  for (int h = 0; h < 2; ++h) {
    float4 v0 = a3p[h * 8 + u * 2];
    float4 v1 = a3p[h * 8 + u * 2 + 1];
    int kb = h * 32 + u * 8;
    u16x8 uu;
    uu[0] = f2bf(fmaxf(fmaf(v0.x, SC[kb+0], CC[kb+0]), 0.f));
    uu[1] = f2bf(fmaxf(fmaf(v0.y, SC[kb+1], CC[kb+1]), 0.f));
    uu[2] = f2bf(fmaxf(fmaf(v0.z, SC[kb+2], CC[kb+2]), 0.f));
    uu[3] = f2bf(fmaxf(fmaf(v0.w, SC[kb+3], CC[kb+3]), 0.f));
    uu[4] = f2bf(fmaxf(fmaf(v1.x, SC[kb+4], CC[kb+4]), 0.f));
    uu[5] = f2bf(fmaxf(fmaf(v1.y, SC[kb+5], CC[kb+5]), 0.f));
    uu[6] = f2bf(fmaxf(fmaf(v1.z, SC[kb+6], CC[kb+6]), 0.f));
    uu[7] = f2bf(fmaxf(fmaf(v1.w, SC[kb+7], CC[kb+7]), 0.f));
    aF[h] = __builtin_bit_cast(bf16x8, uu);
  }

  const unsigned short* wto = (const unsigned short*)(ws + WS_WTO);
  for (int m = 0; m < 3; ++m) {
    __syncthreads();
    const unsigned short* src = wto + (size_t)m * 262144 + (size_t)c0 * 64;
    for (int ch = t; ch < 2048; ch += 256) {
      int n = ch >> 3, kc = ch & 7;
      u16x8 vchunk = *(const u16x8*)(src + n * 64 + kc * 8);
      *(u16x8*)(WB + n * 128 + ((kc ^ (n & 7)) << 4)) = vchunk;
    }
    __syncthreads();
    const float* bias = (m == 0) ? bpi : ((m == 1) ? bm : bth);
    float* po = out + (size_t)m * 67108864;
    for (int cg = 0; cg < 16; ++cg) {
      int n = cg * 16 + li;
      bf16x8 bF0 = *(const bf16x8*)(WB + n * 128 + (((0 + u) ^ (n & 7)) << 4));
      bf16x8 bF1 = *(const bf16x8*)(WB + n * 128 + (((4 + u) ^ (n & 7)) << 4));
      f32x4 d = (f32x4){0.f, 0.f, 0.f, 0.f};
      d = __builtin_amdgcn_mfma_f32_16x16x32_bf16(bF0, aF[0], d, 0, 0, 0);
      d = __builtin_amdgcn_mfma_f32_16x16x32_bf16(bF1, aF[1], d, 0, 0, 0);
      int colb = c0 + cg * 16 + u * 4;
      f32x4 bv = *(const f32x4*)(bias + colb);
      f32x4 z;
      #pragma unroll
      for (int r = 0; r < 4; ++r) {
        float zz = d[r] + bv[r];
        z[r] = (m == 0) ? (1.f / (1.f + __expf(-zz))) : __expf(zz);
      }
      *(f32x4*)(po + (size_t)arow * 4096 + colb) = z;
    }
  }
}

extern "C" void kernel_launch(void* const* d_in, const int* in_sizes, int n_in,
                              void* d_out, int out_size, void* d_ws, size_t ws_size,
                              hipStream_t stream) {
  const float* x    = (const float*)d_in[0];
  const float* Win  = (const float*)d_in[1];
  // d_in[2] = b_in: cancels through BN1, unused.
  const float* g1   = (const float*)d_in[3];
  const float* bt1  = (const float*)d_in[4];
  const float* Wenc = (const float*)d_in[5];
  const float* benc = (const float*)d_in[6];
  const float* g2   = (const float*)d_in[7];
  const float* bt2  = (const float*)d_in[8];
  const float* Wdec = (const float*)d_in[9];
  const float* bdec = (const float*)d_in[10];
  const float* g3   = (const float*)d_in[11];
  const float* bt3  = (const float*)d_in[12];
  const float* Wpi  = (const float*)d_in[13];
  const float* bpi  = (const float*)d_in[14];
  const float* Wm   = (const float*)d_in[15];
  const float* bm   = (const float*)d_in[16];
  const float* Wth  = (const float*)d_in[17];
  const float* bth  = (const float*)d_in[18];
  float* ws  = (float*)d_ws;
  float* out = (float*)d_out;

  hipLaunchKernelGGL(k_prep_rowsum, dim3(4352), dim3(256),  0, stream, x, Win, Wpi, Wm, Wth, ws);
  hipLaunchKernelGGL(k_median,      dim3(1),    dim3(1024), 0, stream, ws);
  hipLaunchKernelGGL(k_passB,       dim3(512),  dim3(512),  0, stream, x, ws);
  hipLaunchKernelGGL(k_layer1,      dim3(256),  dim3(256),  0, stream, g1, bt1, Wenc, benc, ws);
  hipLaunchKernelGGL(k_layer2,      dim3(256),  dim3(256),  0, stream, g2, bt2, Wdec, bdec, ws);
  hipLaunchKernelGGL(k_red3,        dim3(1),    dim3(256),  0, stream, g3, bt3, ws);
  hipLaunchKernelGGL(k_out,         dim3(4096), dim3(256),  0, stream, bpi, bm, bth, out, ws);
}

// Round 8
// 420.996 us; speedup vs baseline: 1.4151x; 1.0249x over previous
//
#include <hip/hip_runtime.h>

#define BATCH 16384
#define DIM   4096

typedef __bf16 bf16x8 __attribute__((ext_vector_type(8)));
typedef float  f32x4  __attribute__((ext_vector_type(4)));
typedef unsigned short u16x8 __attribute__((ext_vector_type(8)));
typedef unsigned short u16x4 __attribute__((ext_vector_type(4)));

// ---- workspace layout (float offsets) ----
#define WS_ROWSUM 0         // 16384
#define WS_MED    16384     // 1
#define WS_NPART  16400     // 512*2
#define WS_SC3    17536     // 64
#define WS_CC3    17600     // 64
#define WS_A2PART 18432     // 256*64
#define WS_A3PART 34816     // 256*128
#define WS_CPART  67584     // 512*128 (per-block col sum[64] then sumsq[64])
#define WS_R      133120    // 16384*64 fp32
#define WS_A2     1181696   // 16384*32 fp32
#define WS_A3     1705984   // 16384*64 fp32
#define WS_WTIN   2754560   // 64*4096 bf16 (as ushort)
#define WS_WTO    2885632   // 3 * 4096*64 bf16

__device__ __forceinline__ unsigned short f2bf(float f){
  union { float f; unsigned u; } v; v.f = f;
  unsigned r = v.u + 0x7FFFu + ((v.u >> 16) & 1u);
  return (unsigned short)(r >> 16);
}

// L0: weight transpose/bf16 prep via LDS (blocks 0..255, coalesced 128B+ writes)
//     + row sums of x (blocks 256..4351).
__global__ __launch_bounds__(256) void k_prep_rowsum(
    const float* __restrict__ x, const float* __restrict__ Win,
    const float* __restrict__ Wpi, const float* __restrict__ Wm,
    const float* __restrict__ Wth, float* __restrict__ ws){
  int b = blockIdx.x, t = threadIdx.x;
  if (b < 256) {
    __shared__ unsigned short tile[64][72];   // 72 -> 144B row stride (16B aligned)
    if (b < 64) {
      int k0 = b * 64;
      int n = t & 63, kb = t >> 6;
      #pragma unroll
      for (int i = 0; i < 16; ++i) {
        int kk = kb * 16 + i;
        tile[n][kk] = f2bf(Win[(size_t)(k0 + kk) * 64 + n]);
      }
      __syncthreads();
      unsigned short* wtin = (unsigned short*)(ws + WS_WTIN);
      int c = t & 7;
      #pragma unroll
      for (int p = 0; p < 2; ++p) {
        int nn = (t >> 3) + p * 32;
        u16x8 v = *(const u16x8*)&tile[nn][c * 8];
        *(u16x8*)(wtin + (size_t)nn * 4096 + k0 + c * 8) = v;
      }
    } else {
      int bm = (b - 64) >> 6;
      int n0 = ((b - 64) & 63) * 64;
      const float* W = (bm == 0) ? Wpi : ((bm == 1) ? Wm : Wth);
      int nn = t & 63, kb = t >> 6;
      #pragma unroll
      for (int i = 0; i < 16; ++i) {
        int k = kb * 16 + i;
        tile[nn][k] = f2bf(W[(size_t)k * 4096 + n0 + nn]);
      }
      __syncthreads();
      unsigned short* wto = (unsigned short*)(ws + WS_WTO);
      int c = t & 7;
      #pragma unroll
      for (int p = 0; p < 2; ++p) {
        int nn2 = (t >> 3) + p * 32;
        u16x8 v = *(const u16x8*)&tile[nn2][c * 8];
        *(u16x8*)(wto + (size_t)bm * 262144 + (size_t)(n0 + nn2) * 64 + c * 8) = v;
      }
    }
  } else {
    int w = t >> 6, lane = t & 63;
    int row = (b - 256) * 4 + w;
    const float4* xr = (const float4*)(x + (size_t)row * DIM);
    float s = 0.f;
    #pragma unroll
    for (int i = 0; i < 16; ++i) {
      float4 v = xr[lane + 64 * i];
      s += (v.x + v.y) + (v.z + v.w);
    }
    #pragma unroll
    for (int m = 32; m; m >>= 1) s += __shfl_xor(s, m);
    if (lane == 0) ws[WS_ROWSUM + row] = s;
  }
}

// L1: exact lower median of 16384 positive floats via 3-pass MSD radix (bits 12/12/8).
__global__ __launch_bounds__(1024) void k_median(float* __restrict__ ws){
  __shared__ unsigned keys[16384];
  __shared__ int hist[4096];
  __shared__ int scanbuf[1024];
  __shared__ int selBin, selRank;
  int t = threadIdx.x, lane = t & 63;

  for (int i = t; i < 16384; i += 1024) keys[i] = __float_as_uint(ws[WS_ROWSUM + i]);
  for (int i = t; i < 4096; i += 1024) hist[i] = 0;
  __syncthreads();

  auto scanFind = [&](int target) {
    int s = hist[4*t] + hist[4*t+1] + hist[4*t+2] + hist[4*t+3];
    scanbuf[t] = s;
    __syncthreads();
    for (int off = 1; off < 1024; off <<= 1) {
      int v = scanbuf[t];
      int a = (t >= off) ? scanbuf[t - off] : 0;
      __syncthreads();
      scanbuf[t] = v + a;
      __syncthreads();
    }
    int acc = scanbuf[t] - s;
    #pragma unroll
    for (int j = 0; j < 4; ++j) {
      int c = hist[4*t + j];
      if (acc <= target && target < acc + c) { selBin = 4*t + j; selRank = target - acc; }
      acc += c;
    }
    __syncthreads();
  };

  for (int i = t; i < 16384; i += 1024) {
    unsigned key = keys[i] >> 20;
    unsigned long long unclaimed = __ballot(1);
    int cnt = 0; bool leader = false;
    while (true) {
      int src = (int)(__ffsll((unsigned long long)unclaimed)) - 1;
      unsigned k0 = (unsigned)__shfl((int)key, src);
      unsigned long long eq = __ballot(k0 == key);
      if (k0 == key) { leader = (lane == src); cnt = (int)__popcll(eq); break; }
      unclaimed &= ~eq;
    }
    if (leader) atomicAdd(&hist[key], cnt);
  }
  __syncthreads();
  scanFind(8191);
  unsigned B1 = (unsigned)selBin; int r1 = selRank;
  __syncthreads();
  for (int i = t; i < 4096; i += 1024) hist[i] = 0;
  __syncthreads();
  for (int i = t; i < 16384; i += 1024) {
    unsigned u = keys[i];
    if ((u >> 20) == B1) atomicAdd(&hist[(u >> 8) & 0xFFF], 1);
  }
  __syncthreads();
  scanFind(r1);
  unsigned B2 = (unsigned)selBin; int r2 = selRank;
  __syncthreads();
  for (int i = t; i < 4096; i += 1024) hist[i] = 0;
  __syncthreads();
  unsigned hi24 = (B1 << 12) | B2;
  for (int i = t; i < 16384; i += 1024) {
    unsigned u = keys[i];
    if ((u >> 8) == hi24) atomicAdd(&hist[u & 0xFF], 1);
  }
  __syncthreads();
  scanFind(r2);
  if (t == 0) {
    unsigned bits = (B1 << 20) | (B2 << 8) | (unsigned)selBin;
    ws[WS_MED] = __uint_as_float(bits);
  }
}

// L2: fused norm + R = norm @ W_in, per-block column sum/sumsq of R, global norm stats.
// BM=32 rows, grid 512, ONE barrier per K-step, FOUR-deep register prefetch.
// REVERSE row order: k_prep's rowsum streamed x through L3 ascending, so L3 holds
// the high rows; processing them first makes early x-reads L3 hits.
__global__ __launch_bounds__(512) void k_passB(const float* __restrict__ x, float* __restrict__ ws){
  __shared__ __align__(16) char Ab[2 * 4096];
  __shared__ __align__(16) char Bb[2 * 8192];
  __shared__ float ainv_s[32];
  __shared__ float redn[8][2];
  __shared__ float cpart[2][64], cqpart[2][64];

  const unsigned short* wtin = (const unsigned short*)(ws + WS_WTIN);
  int tid = threadIdx.x;
  int r0 = (511 - (int)blockIdx.x) * 32;     // reverse order for L3 reuse
  float med = ws[WS_MED];
  if (tid < 32) ainv_s[tid] = med / ws[WS_ROWSUM + r0 + tid];
  __syncthreads();

  int w = tid >> 6, lane = tid & 63;
  int li = lane & 15, u = lane >> 4;
  int wrb = (w & 1) * 16;
  int wc  = (w >> 1) * 16;

  int xrow = tid >> 4;
  int xcol0 = (tid & 15) * 4;
  int wn = tid >> 3, wkc = tid & 7;
  float ainv = ainv_s[xrow];

  f32x4 acc = (f32x4){0.f, 0.f, 0.f, 0.f};
  float nsum = 0.f, nsq = 0.f;
  float4 xa0, xa1, xa2, xa3; u16x8 wv0, wv1, wv2, wv3;

  auto LOADT = [&](int tt, float4& xv, u16x8& wq){
    int coff = tt * 64;
    xv = *(const float4*)(x + (size_t)(r0 + xrow) * DIM + coff + xcol0);
    wq = *(const u16x8*)(wtin + (size_t)wn * DIM + coff + wkc * 8);
  };
  auto WRITET = [&](int buf, const float4& xv, const u16x8& wq){
    float n0 = __logf(fmaf(xv.x, ainv, 1.f));
    float n1 = __logf(fmaf(xv.y, ainv, 1.f));
    float n2 = __logf(fmaf(xv.z, ainv, 1.f));
    float n3 = __logf(fmaf(xv.w, ainv, 1.f));
    nsum += (n0 + n1) + (n2 + n3);
    nsq  += (n0*n0 + n1*n1) + (n2*n2 + n3*n3);
    u16x4 p = { f2bf(n0), f2bf(n1), f2bf(n2), f2bf(n3) };
    int c = xcol0 >> 3, sub = (xcol0 >> 2) & 1;
    *(u16x4*)(Ab + buf * 4096 + xrow * 128 + ((c ^ (xrow & 7)) << 4) + sub * 8) = p;
    *(u16x8*)(Bb + buf * 8192 + wn * 128 + ((wkc ^ (wn & 7)) << 4)) = wq;
  };
  int arow = wrb + li, brow = wc + li;
  auto DOMFMA = [&](int p){
    const char* Au = Ab + p * 4096;
    const char* Bu = Bb + p * 8192;
    #pragma unroll
    for (int kk = 0; kk < 2; ++kk) {
      bf16x8 aF = *(const bf16x8*)(Au + arow * 128 + (((kk * 4 + u) ^ (arow & 7)) << 4));
      bf16x8 bF = *(const bf16x8*)(Bu + brow * 128 + (((kk * 4 + u) ^ (brow & 7)) << 4));
      acc = __builtin_amdgcn_mfma_f32_16x16x32_bf16(bF, aF, acc, 0, 0, 0);
    }
  };

  // preamble: tiles 0,1,2 in sets s0,s1,s2; tile 0 staged to buf0.
  LOADT(0, xa0, wv0);
  LOADT(1, xa1, wv1);
  LOADT(2, xa2, wv2);
  WRITET(0, xa0, wv0);
  __syncthreads();
  for (int t = 0; t < 64; t += 4) {
    if (t + 3 < 64) LOADT(t + 3, xa3, wv3);
    WRITET(1, xa1, wv1);
    DOMFMA(0);
    __syncthreads();
    if (t + 4 < 64) LOADT(t + 4, xa0, wv0);
    WRITET(0, xa2, wv2);
    DOMFMA(1);
    __syncthreads();
    if (t + 5 < 64) LOADT(t + 5, xa1, wv1);
    if (t + 3 < 64) WRITET(1, xa3, wv3);
    DOMFMA(0);
    __syncthreads();
    if (t + 6 < 64) LOADT(t + 6, xa2, wv2);
    if (t + 4 < 64) WRITET(0, xa0, wv0);
    DOMFMA(1);
    __syncthreads();
  }

  float* R = ws + WS_R;
  *(f32x4*)(R + (size_t)(r0 + wrb + li) * 64 + wc + u * 4) = acc;

  float s0 = acc[0], s1 = acc[1], s2 = acc[2], s3 = acc[3];
  float q0 = acc[0]*acc[0], q1 = acc[1]*acc[1], q2 = acc[2]*acc[2], q3 = acc[3]*acc[3];
  #pragma unroll
  for (int m = 1; m < 16; m <<= 1) {
    s0 += __shfl_xor(s0, m); s1 += __shfl_xor(s1, m);
    s2 += __shfl_xor(s2, m); s3 += __shfl_xor(s3, m);
    q0 += __shfl_xor(q0, m); q1 += __shfl_xor(q1, m);
    q2 += __shfl_xor(q2, m); q3 += __shfl_xor(q3, m);
  }
  if (li == 0) {
    int cb = wc + u * 4;
    cpart[w & 1][cb + 0] = s0; cpart[w & 1][cb + 1] = s1;
    cpart[w & 1][cb + 2] = s2; cpart[w & 1][cb + 3] = s3;
    cqpart[w & 1][cb + 0] = q0; cqpart[w & 1][cb + 1] = q1;
    cqpart[w & 1][cb + 2] = q2; cqpart[w & 1][cb + 3] = q3;
  }
  #pragma unroll
  for (int m = 32; m; m >>= 1) { nsum += __shfl_xor(nsum, m); nsq += __shfl_xor(nsq, m); }
  if (lane == 0) { redn[w][0] = nsum; redn[w][1] = nsq; }
  __syncthreads();
  if (tid < 64) {
    ws[WS_CPART + blockIdx.x * 128 + tid]      = cpart[0][tid] + cpart[1][tid];
    ws[WS_CPART + blockIdx.x * 128 + 64 + tid] = cqpart[0][tid] + cqpart[1][tid];
  }
  if (tid == 0) {
    float S = 0.f, Q = 0.f;
    for (int i = 0; i < 8; ++i) { S += redn[i][0]; Q += redn[i][1]; }
    ws[WS_NPART + blockIdx.x * 2]     = S;
    ws[WS_NPART + blockIdx.x * 2 + 1] = Q;
  }
}

// L3: BN1 finalize + h1 = relu(BN1(R)), a2 = h1 @ W_enc + b_enc, a2 partials.
__global__ __launch_bounds__(256) void k_layer1(const float* __restrict__ g1, const float* __restrict__ bt1,
                         const float* __restrict__ Wenc, const float* __restrict__ benc,
                         float* __restrict__ ws){
  __shared__ float sc1[64], cc1[64];
  __shared__ float h1[64][65];
  __shared__ float we[64][33];
  __shared__ float sred[4][64], qred[4][64];
  __shared__ float sigred[4][2];
  __shared__ float sig2s;
  int t = threadIdx.x, lane = t & 63, w4 = t >> 6;

  {
    float s = 0.f, q = 0.f;
    for (int b = t; b < 512; b += 256) { s += ws[WS_NPART + b * 2]; q += ws[WS_NPART + b * 2 + 1]; }
    #pragma unroll
    for (int m = 32; m; m >>= 1) { s += __shfl_xor(s, m); q += __shfl_xor(q, m); }
    if (lane == 0) { sigred[w4][0] = s; sigred[w4][1] = q; }
  }
  {
    int col = t & 63, grp = t >> 6;
    float S = 0.f, Q = 0.f;
    for (int b = grp * 128; b < grp * 128 + 128; ++b) {
      S += ws[WS_CPART + b * 128 + col];
      Q += ws[WS_CPART + b * 128 + 64 + col];
    }
    sred[grp][col] = S; qred[grp][col] = Q;
  }
  for (int i = t; i < 2048; i += 256) we[i >> 5][i & 31] = Wenc[i];
  __syncthreads();
  if (t == 0) {
    double Sn = (double)sigred[0][0] + sigred[1][0] + sigred[2][0] + sigred[3][0];
    double Qn = (double)sigred[0][1] + sigred[1][1] + sigred[2][1] + sigred[3][1];
    double N = 67108864.0;
    sig2s = (float)((Qn - Sn * Sn / N) / (N - 1.0));
  }
  __syncthreads();
  if (t < 64) {
    float Sc = sred[0][t] + sred[1][t] + sred[2][t] + sred[3][t];
    float Qc = qred[0][t] + qred[1][t] + qred[2][t] + qred[3][t];
    float cm = Sc * (1.f / 16384.f);
    float cv = Qc * (1.f / 16384.f) - cm * cm;
    float sc = g1[t] * rsqrtf(cv + sig2s * 1e-5f);
    sc1[t] = sc; cc1[t] = bt1[t] - cm * sc;
  }
  __syncthreads();

  int r0 = blockIdx.x * 64;
  const float* R = ws + WS_R;
  for (int i = t; i < 4096; i += 256) {
    int row = i >> 6, col = i & 63;
    float v = fmaf(R[(size_t)(r0 + row) * 64 + col], sc1[col], cc1[col]);
    h1[row][col] = fmaxf(v, 0.f);
  }
  __syncthreads();
  int row = t & 63, cb = t >> 6;
  float a[8];
  #pragma unroll
  for (int j = 0; j < 8; ++j) a[j] = benc[cb * 8 + j];
  for (int k = 0; k < 64; ++k) {
    float hv = h1[row][k];
    #pragma unroll
    for (int j = 0; j < 8; ++j) a[j] = fmaf(hv, we[k][cb * 8 + j], a[j]);
  }
  float* A2 = ws + WS_A2;
  #pragma unroll
  for (int j = 0; j < 8; ++j) A2[(size_t)(r0 + row) * 32 + cb * 8 + j] = a[j];
  #pragma unroll
  for (int j = 0; j < 8; ++j) {
    float s = a[j], q = a[j] * a[j];
    #pragma unroll
    for (int m = 32; m; m >>= 1) { s += __shfl_xor(s, m); q += __shfl_xor(q, m); }
    if (lane == 0) {
      int c = cb * 8 + j;
      ws[WS_A2PART + blockIdx.x * 64 + c * 2]     = s;
      ws[WS_A2PART + blockIdx.x * 64 + c * 2 + 1] = q;
    }
  }
}

// L4: BN2 finalize + h2 = relu(BN2(a2)), a3 = h2 @ W_dec + b_dec, a3 partials.
__global__ __launch_bounds__(256) void k_layer2(const float* __restrict__ g2, const float* __restrict__ bt2,
                         const float* __restrict__ Wdec, const float* __restrict__ bdec,
                         float* __restrict__ ws){
  __shared__ float h2[64][33];
  __shared__ float wd[32][65];
  __shared__ float sc2[32], cc2[32];
  __shared__ float sred2[8][32], qred2[8][32];
  int t = threadIdx.x, lane = t & 63;
  {
    int col = t & 31, grp = t >> 5;
    float S = 0.f, Q = 0.f;
    for (int b = grp * 32; b < grp * 32 + 32; ++b) {
      S += ws[WS_A2PART + b * 64 + col * 2];
      Q += ws[WS_A2PART + b * 64 + col * 2 + 1];
    }
    sred2[grp][col] = S; qred2[grp][col] = Q;
  }
  for (int i = t; i < 2048; i += 256) wd[i >> 6][i & 63] = Wdec[i];
  __syncthreads();
  if (t < 32) {
    float Sc = 0.f, Qc = 0.f;
    #pragma unroll
    for (int g = 0; g < 8; ++g) { Sc += sred2[g][t]; Qc += qred2[g][t]; }
    float cm = Sc * (1.f / 16384.f);
    float cv = Qc * (1.f / 16384.f) - cm * cm;
    float sc = g2[t] * rsqrtf(cv + 1e-5f);
    sc2[t] = sc; cc2[t] = bt2[t] - cm * sc;
  }
  __syncthreads();
  int r0 = blockIdx.x * 64;
  const float* A2 = ws + WS_A2;
  for (int i = t; i < 2048; i += 256) {
    int row = i >> 5, col = i & 31;
    float v = fmaf(A2[(size_t)(r0 + row) * 32 + col], sc2[col], cc2[col]);
    h2[row][col] = fmaxf(v, 0.f);
  }
  __syncthreads();
  int row = t & 63, cb = t >> 6;
  float a[16];
  #pragma unroll
  for (int j = 0; j < 16; ++j) a[j] = bdec[cb * 16 + j];
  for (int k = 0; k < 32; ++k) {
    float hv = h2[row][k];
    #pragma unroll
    for (int j = 0; j < 16; ++j) a[j] = fmaf(hv, wd[k][cb * 16 + j], a[j]);
  }
  float* A3 = ws + WS_A3;
  #pragma unroll
  for (int j = 0; j < 16; ++j) A3[(size_t)(r0 + row) * 64 + cb * 16 + j] = a[j];
  #pragma unroll
  for (int j = 0; j < 16; ++j) {
    float s = a[j], q = a[j] * a[j];
    #pragma unroll
    for (int m = 32; m; m >>= 1) { s += __shfl_xor(s, m); q += __shfl_xor(q, m); }
    if (lane == 0) {
      int c = cb * 16 + j;
      ws[WS_A3PART + blockIdx.x * 128 + c * 2]     = s;
      ws[WS_A3PART + blockIdx.x * 128 + c * 2 + 1] = q;
    }
  }
}

// L5: reduce a3 partials -> BN3 scale/shift.
__global__ void k_red3(const float* __restrict__ g3, const float* __restrict__ bt3, float* __restrict__ ws){
  __shared__ float red[128];
  int t = threadIdx.x;
  if (t < 128) {
    float s = 0.f;
    for (int b = 0; b < 256; ++b) s += ws[WS_A3PART + b * 128 + t];
    red[t] = s;
  }
  __syncthreads();
  if (t < 64) {
    float S = red[2 * t], Q = red[2 * t + 1];
    float cm = S * (1.f / 16384.f);
    float cv = Q * (1.f / 16384.f) - cm * cm;
    float sc = g3[t] * rsqrtf(cv + 1e-5f);
    ws[WS_SC3 + t] = sc; ws[WS_CC3 + t] = bt3[t] - cm * sc;
  }
}

// L6: heads. h3 = relu(BN3(a3)) in-register; out = act(h3 @ W + b).
// 128 rows x 256 cols per block (512 thr, 8 waves): weight staging amortized over
// 2x rows vs round 7; total WTO L2 traffic halved.
__global__ __launch_bounds__(512) void k_out(const float* __restrict__ bpi, const float* __restrict__ bm,
                      const float* __restrict__ bth, float* __restrict__ out,
                      float* __restrict__ ws){
  __shared__ __align__(16) char WB[256 * 128];   // [256 n][64 k] bf16, XOR-swizzled
  int t = threadIdx.x;
  int bx = blockIdx.x;
  int rb = bx >> 4, cb = bx & 15;
  int r0 = rb * 128, c0 = cb * 256;
  int w = t >> 6, lane = t & 63;
  int u = lane >> 4, li = lane & 15;

  const float* A3 = ws + WS_A3;
  const float* SC = ws + WS_SC3;
  const float* CC = ws + WS_CC3;
  int arow = r0 + w * 16 + li;
  const float4* a3p = (const float4*)(A3 + (size_t)arow * 64);
  bf16x8 aF[2];
  #pragma unroll
  for (int h = 0; h < 2; ++h) {
    float4 v0 = a3p[h * 8 + u * 2];
    float4 v1 = a3p[h * 8 + u * 2 + 1];
    int kb = h * 32 + u * 8;
    u16x8 uu;
    uu[0] = f2bf(fmaxf(fmaf(v0.x, SC[kb+0], CC[kb+0]), 0.f));
    uu[1] = f2bf(fmaxf(fmaf(v0.y, SC[kb+1], CC[kb+1]), 0.f));
    uu[2] = f2bf(fmaxf(fmaf(v0.z, SC[kb+2], CC[kb+2]), 0.f));
    uu[3] = f2bf(fmaxf(fmaf(v0.w, SC[kb+3], CC[kb+3]), 0.f));
    uu[4] = f2bf(fmaxf(fmaf(v1.x, SC[kb+4], CC[kb+4]), 0.f));
    uu[5] = f2bf(fmaxf(fmaf(v1.y, SC[kb+5], CC[kb+5]), 0.f));
    uu[6] = f2bf(fmaxf(fmaf(v1.z, SC[kb+6], CC[kb+6]), 0.f));
    uu[7] = f2bf(fmaxf(fmaf(v1.w, SC[kb+7], CC[kb+7]), 0.f));
    aF[h] = __builtin_bit_cast(bf16x8, uu);
  }

  const unsigned short* wto = (const unsigned short*)(ws + WS_WTO);
  for (int m = 0; m < 3; ++m) {
    __syncthreads();
    const unsigned short* src = wto + (size_t)m * 262144 + (size_t)c0 * 64;
    for (int ch = t; ch < 2048; ch += 512) {
      int n = ch >> 3, kc = ch & 7;
      u16x8 vchunk = *(const u16x8*)(src + n * 64 + kc * 8);
      *(u16x8*)(WB + n * 128 + ((kc ^ (n & 7)) << 4)) = vchunk;
    }
    __syncthreads();
    const float* bias = (m == 0) ? bpi : ((m == 1) ? bm : bth);
    float* po = out + (size_t)m * 67108864;
    for (int cg = 0; cg < 16; ++cg) {
      int n = cg * 16 + li;
      bf16x8 bF0 = *(const bf16x8*)(WB + n * 128 + (((0 + u) ^ (n & 7)) << 4));
      bf16x8 bF1 = *(const bf16x8*)(WB + n * 128 + (((4 + u) ^ (n & 7)) << 4));
      f32x4 d = (f32x4){0.f, 0.f, 0.f, 0.f};
      d = __builtin_amdgcn_mfma_f32_16x16x32_bf16(bF0, aF[0], d, 0, 0, 0);
      d = __builtin_amdgcn_mfma_f32_16x16x32_bf16(bF1, aF[1], d, 0, 0, 0);
      int colb = c0 + cg * 16 + u * 4;
      f32x4 bv = *(const f32x4*)(bias + colb);
      f32x4 z;
      #pragma unroll
      for (int r = 0; r < 4; ++r) {
        float zz = d[r] + bv[r];
        z[r] = (m == 0) ? (1.f / (1.f + __expf(-zz))) : __expf(zz);
      }
      *(f32x4*)(po + (size_t)arow * 4096 + colb) = z;
    }
  }
}

extern "C" void kernel_launch(void* const* d_in, const int* in_sizes, int n_in,
                              void* d_out, int out_size, void* d_ws, size_t ws_size,
                              hipStream_t stream) {
  const float* x    = (const float*)d_in[0];
  const float* Win  = (const float*)d_in[1];
  // d_in[2] = b_in: cancels through BN1, unused.
  const float* g1   = (const float*)d_in[3];
  const float* bt1  = (const float*)d_in[4];
  const float* Wenc = (const float*)d_in[5];
  const float* benc = (const float*)d_in[6];
  const float* g2   = (const float*)d_in[7];
  const float* bt2  = (const float*)d_in[8];
  const float* Wdec = (const float*)d_in[9];
  const float* bdec = (const float*)d_in[10];
  const float* g3   = (const float*)d_in[11];
  const float* bt3  = (const float*)d_in[12];
  const float* Wpi  = (const float*)d_in[13];
  const float* bpi  = (const float*)d_in[14];
  const float* Wm   = (const float*)d_in[15];
  const float* bm   = (const float*)d_in[16];
  const float* Wth  = (const float*)d_in[17];
  const float* bth  = (const float*)d_in[18];
  float* ws  = (float*)d_ws;
  float* out = (float*)d_out;

  hipLaunchKernelGGL(k_prep_rowsum, dim3(4352), dim3(256),  0, stream, x, Win, Wpi, Wm, Wth, ws);
  hipLaunchKernelGGL(k_median,      dim3(1),    dim3(1024), 0, stream, ws);
  hipLaunchKernelGGL(k_passB,       dim3(512),  dim3(512),  0, stream, x, ws);
  hipLaunchKernelGGL(k_layer1,      dim3(256),  dim3(256),  0, stream, g1, bt1, Wenc, benc, ws);
  hipLaunchKernelGGL(k_layer2,      dim3(256),  dim3(256),  0, stream, g2, bt2, Wdec, bdec, ws);
  hipLaunchKernelGGL(k_red3,        dim3(1),    dim3(256),  0, stream, g3, bt3, ws);
  hipLaunchKernelGGL(k_out,         dim3(2048), dim3(512),  0, stream, bpi, bm, bth, out, ws);
}

// Round 9
// 413.451 us; speedup vs baseline: 1.4409x; 1.0182x over previous
//
#include <hip/hip_runtime.h>

#define BATCH 16384
#define DIM   4096

typedef __bf16 bf16x8 __attribute__((ext_vector_type(8)));
typedef float  f32x4  __attribute__((ext_vector_type(4)));
typedef unsigned short u16x8 __attribute__((ext_vector_type(8)));
typedef unsigned short u16x4 __attribute__((ext_vector_type(4)));

// Raw barrier: LDS-visibility fence only. Skips the vmcnt(0) drain that
// __syncthreads() forces (which would wait for in-flight register prefetch
// loads and output stores). lgkmcnt(0) covers ds_write/ds_read ordering.
#define BAR_LGKM() asm volatile("s_waitcnt lgkmcnt(0)\ns_barrier" ::: "memory")

// ---- workspace layout (float offsets) ----
#define WS_ROWSUM 0         // 16384
#define WS_MED    16384     // 1
#define WS_NPART  16400     // 512*2
#define WS_SC3    17536     // 64
#define WS_CC3    17600     // 64
#define WS_A2PART 18432     // 256*64
#define WS_A3PART 34816     // 256*128
#define WS_CPART  67584     // 512*128 (per-block col sum[64] then sumsq[64])
#define WS_R      133120    // 16384*64 fp32
#define WS_A2     1181696   // 16384*32 fp32
#define WS_A3     1705984   // 16384*64 fp32
#define WS_WTIN   2754560   // 64*4096 bf16 (as ushort)
#define WS_WTO    2885632   // 3 * 4096*64 bf16

__device__ __forceinline__ unsigned short f2bf(float f){
  union { float f; unsigned u; } v; v.f = f;
  unsigned r = v.u + 0x7FFFu + ((v.u >> 16) & 1u);
  return (unsigned short)(r >> 16);
}

// L0: weight transpose/bf16 prep via LDS (blocks 0..255, coalesced 128B+ writes)
//     + row sums of x (blocks 256..4351).
__global__ __launch_bounds__(256) void k_prep_rowsum(
    const float* __restrict__ x, const float* __restrict__ Win,
    const float* __restrict__ Wpi, const float* __restrict__ Wm,
    const float* __restrict__ Wth, float* __restrict__ ws){
  int b = blockIdx.x, t = threadIdx.x;
  if (b < 256) {
    __shared__ unsigned short tile[64][72];   // 72 -> 144B row stride (16B aligned)
    if (b < 64) {
      int k0 = b * 64;
      int n = t & 63, kb = t >> 6;
      #pragma unroll
      for (int i = 0; i < 16; ++i) {
        int kk = kb * 16 + i;
        tile[n][kk] = f2bf(Win[(size_t)(k0 + kk) * 64 + n]);
      }
      __syncthreads();
      unsigned short* wtin = (unsigned short*)(ws + WS_WTIN);
      int c = t & 7;
      #pragma unroll
      for (int p = 0; p < 2; ++p) {
        int nn = (t >> 3) + p * 32;
        u16x8 v = *(const u16x8*)&tile[nn][c * 8];
        *(u16x8*)(wtin + (size_t)nn * 4096 + k0 + c * 8) = v;
      }
    } else {
      int bm = (b - 64) >> 6;
      int n0 = ((b - 64) & 63) * 64;
      const float* W = (bm == 0) ? Wpi : ((bm == 1) ? Wm : Wth);
      int nn = t & 63, kb = t >> 6;
      #pragma unroll
      for (int i = 0; i < 16; ++i) {
        int k = kb * 16 + i;
        tile[nn][k] = f2bf(W[(size_t)k * 4096 + n0 + nn]);
      }
      __syncthreads();
      unsigned short* wto = (unsigned short*)(ws + WS_WTO);
      int c = t & 7;
      #pragma unroll
      for (int p = 0; p < 2; ++p) {
        int nn2 = (t >> 3) + p * 32;
        u16x8 v = *(const u16x8*)&tile[nn2][c * 8];
        *(u16x8*)(wto + (size_t)bm * 262144 + (size_t)(n0 + nn2) * 64 + c * 8) = v;
      }
    }
  } else {
    int w = t >> 6, lane = t & 63;
    int row = (b - 256) * 4 + w;
    const float4* xr = (const float4*)(x + (size_t)row * DIM);
    float s = 0.f;
    #pragma unroll
    for (int i = 0; i < 16; ++i) {
      float4 v = xr[lane + 64 * i];
      s += (v.x + v.y) + (v.z + v.w);
    }
    #pragma unroll
    for (int m = 32; m; m >>= 1) s += __shfl_xor(s, m);
    if (lane == 0) ws[WS_ROWSUM + row] = s;
  }
}

// L1: exact lower median of 16384 positive floats via 3-pass MSD radix (bits 12/12/8).
__global__ __launch_bounds__(1024) void k_median(float* __restrict__ ws){
  __shared__ unsigned keys[16384];
  __shared__ int hist[4096];
  __shared__ int scanbuf[1024];
  __shared__ int selBin, selRank;
  int t = threadIdx.x, lane = t & 63;

  for (int i = t; i < 16384; i += 1024) keys[i] = __float_as_uint(ws[WS_ROWSUM + i]);
  for (int i = t; i < 4096; i += 1024) hist[i] = 0;
  __syncthreads();

  auto scanFind = [&](int target) {
    int s = hist[4*t] + hist[4*t+1] + hist[4*t+2] + hist[4*t+3];
    scanbuf[t] = s;
    __syncthreads();
    for (int off = 1; off < 1024; off <<= 1) {
      int v = scanbuf[t];
      int a = (t >= off) ? scanbuf[t - off] : 0;
      __syncthreads();
      scanbuf[t] = v + a;
      __syncthreads();
    }
    int acc = scanbuf[t] - s;
    #pragma unroll
    for (int j = 0; j < 4; ++j) {
      int c = hist[4*t + j];
      if (acc <= target && target < acc + c) { selBin = 4*t + j; selRank = target - acc; }
      acc += c;
    }
    __syncthreads();
  };

  for (int i = t; i < 16384; i += 1024) {
    unsigned key = keys[i] >> 20;
    unsigned long long unclaimed = __ballot(1);
    int cnt = 0; bool leader = false;
    while (true) {
      int src = (int)(__ffsll((unsigned long long)unclaimed)) - 1;
      unsigned k0 = (unsigned)__shfl((int)key, src);
      unsigned long long eq = __ballot(k0 == key);
      if (k0 == key) { leader = (lane == src); cnt = (int)__popcll(eq); break; }
      unclaimed &= ~eq;
    }
    if (leader) atomicAdd(&hist[key], cnt);
  }
  __syncthreads();
  scanFind(8191);
  unsigned B1 = (unsigned)selBin; int r1 = selRank;
  __syncthreads();
  for (int i = t; i < 4096; i += 1024) hist[i] = 0;
  __syncthreads();
  for (int i = t; i < 16384; i += 1024) {
    unsigned u = keys[i];
    if ((u >> 20) == B1) atomicAdd(&hist[(u >> 8) & 0xFFF], 1);
  }
  __syncthreads();
  scanFind(r1);
  unsigned B2 = (unsigned)selBin; int r2 = selRank;
  __syncthreads();
  for (int i = t; i < 4096; i += 1024) hist[i] = 0;
  __syncthreads();
  unsigned hi24 = (B1 << 12) | B2;
  for (int i = t; i < 16384; i += 1024) {
    unsigned u = keys[i];
    if ((u >> 8) == hi24) atomicAdd(&hist[u & 0xFF], 1);
  }
  __syncthreads();
  scanFind(r2);
  if (t == 0) {
    unsigned bits = (B1 << 20) | (B2 << 8) | (unsigned)selBin;
    ws[WS_MED] = __uint_as_float(bits);
  }
}

// L2: fused norm + R = norm @ W_in, per-block column sum/sumsq of R, global norm stats.
// BM=32 rows, grid 512, one RAW barrier per K-step (lgkmcnt only -> prefetch loads
// stay in flight across barriers), FOUR-deep register prefetch, reverse row order.
__global__ __launch_bounds__(512) void k_passB(const float* __restrict__ x, float* __restrict__ ws){
  __shared__ __align__(16) char Ab[2 * 4096];
  __shared__ __align__(16) char Bb[2 * 8192];
  __shared__ float ainv_s[32];
  __shared__ float redn[8][2];
  __shared__ float cpart[2][64], cqpart[2][64];

  const unsigned short* wtin = (const unsigned short*)(ws + WS_WTIN);
  int tid = threadIdx.x;
  int r0 = (511 - (int)blockIdx.x) * 32;     // reverse order for L3 reuse
  float med = ws[WS_MED];
  if (tid < 32) ainv_s[tid] = med / ws[WS_ROWSUM + r0 + tid];
  __syncthreads();

  int w = tid >> 6, lane = tid & 63;
  int li = lane & 15, u = lane >> 4;
  int wrb = (w & 1) * 16;
  int wc  = (w >> 1) * 16;

  int xrow = tid >> 4;
  int xcol0 = (tid & 15) * 4;
  int wn = tid >> 3, wkc = tid & 7;
  float ainv = ainv_s[xrow];

  f32x4 acc = (f32x4){0.f, 0.f, 0.f, 0.f};
  float nsum = 0.f, nsq = 0.f;
  float4 xa0, xa1, xa2, xa3; u16x8 wv0, wv1, wv2, wv3;

  auto LOADT = [&](int tt, float4& xv, u16x8& wq){
    int coff = tt * 64;
    xv = *(const float4*)(x + (size_t)(r0 + xrow) * DIM + coff + xcol0);
    wq = *(const u16x8*)(wtin + (size_t)wn * DIM + coff + wkc * 8);
  };
  auto WRITET = [&](int buf, const float4& xv, const u16x8& wq){
    float n0 = __logf(fmaf(xv.x, ainv, 1.f));
    float n1 = __logf(fmaf(xv.y, ainv, 1.f));
    float n2 = __logf(fmaf(xv.z, ainv, 1.f));
    float n3 = __logf(fmaf(xv.w, ainv, 1.f));
    nsum += (n0 + n1) + (n2 + n3);
    nsq  += (n0*n0 + n1*n1) + (n2*n2 + n3*n3);
    u16x4 p = { f2bf(n0), f2bf(n1), f2bf(n2), f2bf(n3) };
    int c = xcol0 >> 3, sub = (xcol0 >> 2) & 1;
    *(u16x4*)(Ab + buf * 4096 + xrow * 128 + ((c ^ (xrow & 7)) << 4) + sub * 8) = p;
    *(u16x8*)(Bb + buf * 8192 + wn * 128 + ((wkc ^ (wn & 7)) << 4)) = wq;
  };
  int arow = wrb + li, brow = wc + li;
  auto DOMFMA = [&](int p){
    const char* Au = Ab + p * 4096;
    const char* Bu = Bb + p * 8192;
    #pragma unroll
    for (int kk = 0; kk < 2; ++kk) {
      bf16x8 aF = *(const bf16x8*)(Au + arow * 128 + (((kk * 4 + u) ^ (arow & 7)) << 4));
      bf16x8 bF = *(const bf16x8*)(Bu + brow * 128 + (((kk * 4 + u) ^ (brow & 7)) << 4));
      acc = __builtin_amdgcn_mfma_f32_16x16x32_bf16(bF, aF, acc, 0, 0, 0);
    }
  };

  // preamble: tiles 0,1,2 in sets s0,s1,s2; tile 0 staged to buf0.
  LOADT(0, xa0, wv0);
  LOADT(1, xa1, wv1);
  LOADT(2, xa2, wv2);
  WRITET(0, xa0, wv0);
  BAR_LGKM();
  for (int t = 0; t < 64; t += 4) {
    if (t + 3 < 64) LOADT(t + 3, xa3, wv3);
    WRITET(1, xa1, wv1);
    DOMFMA(0);
    BAR_LGKM();
    if (t + 4 < 64) LOADT(t + 4, xa0, wv0);
    WRITET(0, xa2, wv2);
    DOMFMA(1);
    BAR_LGKM();
    if (t + 5 < 64) LOADT(t + 5, xa1, wv1);
    if (t + 3 < 64) WRITET(1, xa3, wv3);
    DOMFMA(0);
    BAR_LGKM();
    if (t + 6 < 64) LOADT(t + 6, xa2, wv2);
    if (t + 4 < 64) WRITET(0, xa0, wv0);
    DOMFMA(1);
    BAR_LGKM();
  }

  float* R = ws + WS_R;
  *(f32x4*)(R + (size_t)(r0 + wrb + li) * 64 + wc + u * 4) = acc;

  float s0 = acc[0], s1 = acc[1], s2 = acc[2], s3 = acc[3];
  float q0 = acc[0]*acc[0], q1 = acc[1]*acc[1], q2 = acc[2]*acc[2], q3 = acc[3]*acc[3];
  #pragma unroll
  for (int m = 1; m < 16; m <<= 1) {
    s0 += __shfl_xor(s0, m); s1 += __shfl_xor(s1, m);
    s2 += __shfl_xor(s2, m); s3 += __shfl_xor(s3, m);
    q0 += __shfl_xor(q0, m); q1 += __shfl_xor(q1, m);
    q2 += __shfl_xor(q2, m); q3 += __shfl_xor(q3, m);
  }
  if (li == 0) {
    int cb = wc + u * 4;
    cpart[w & 1][cb + 0] = s0; cpart[w & 1][cb + 1] = s1;
    cpart[w & 1][cb + 2] = s2; cpart[w & 1][cb + 3] = s3;
    cqpart[w & 1][cb + 0] = q0; cqpart[w & 1][cb + 1] = q1;
    cqpart[w & 1][cb + 2] = q2; cqpart[w & 1][cb + 3] = q3;
  }
  #pragma unroll
  for (int m = 32; m; m >>= 1) { nsum += __shfl_xor(nsum, m); nsq += __shfl_xor(nsq, m); }
  if (lane == 0) { redn[w][0] = nsum; redn[w][1] = nsq; }
  BAR_LGKM();
  if (tid < 64) {
    ws[WS_CPART + blockIdx.x * 128 + tid]      = cpart[0][tid] + cpart[1][tid];
    ws[WS_CPART + blockIdx.x * 128 + 64 + tid] = cqpart[0][tid] + cqpart[1][tid];
  }
  if (tid == 0) {
    float S = 0.f, Q = 0.f;
    for (int i = 0; i < 8; ++i) { S += redn[i][0]; Q += redn[i][1]; }
    ws[WS_NPART + blockIdx.x * 2]     = S;
    ws[WS_NPART + blockIdx.x * 2 + 1] = Q;
  }
}

// L3: BN1 finalize + h1 = relu(BN1(R)), a2 = h1 @ W_enc + b_enc, a2 partials.
__global__ __launch_bounds__(256) void k_layer1(const float* __restrict__ g1, const float* __restrict__ bt1,
                         const float* __restrict__ Wenc, const float* __restrict__ benc,
                         float* __restrict__ ws){
  __shared__ float sc1[64], cc1[64];
  __shared__ float h1[64][65];
  __shared__ float we[64][33];
  __shared__ float sred[4][64], qred[4][64];
  __shared__ float sigred[4][2];
  __shared__ float sig2s;
  int t = threadIdx.x, lane = t & 63, w4 = t >> 6;

  {
    float s = 0.f, q = 0.f;
    for (int b = t; b < 512; b += 256) { s += ws[WS_NPART + b * 2]; q += ws[WS_NPART + b * 2 + 1]; }
    #pragma unroll
    for (int m = 32; m; m >>= 1) { s += __shfl_xor(s, m); q += __shfl_xor(q, m); }
    if (lane == 0) { sigred[w4][0] = s; sigred[w4][1] = q; }
  }
  {
    int col = t & 63, grp = t >> 6;
    float S = 0.f, Q = 0.f;
    for (int b = grp * 128; b < grp * 128 + 128; ++b) {
      S += ws[WS_CPART + b * 128 + col];
      Q += ws[WS_CPART + b * 128 + 64 + col];
    }
    sred[grp][col] = S; qred[grp][col] = Q;
  }
  for (int i = t; i < 2048; i += 256) we[i >> 5][i & 31] = Wenc[i];
  __syncthreads();
  if (t == 0) {
    double Sn = (double)sigred[0][0] + sigred[1][0] + sigred[2][0] + sigred[3][0];
    double Qn = (double)sigred[0][1] + sigred[1][1] + sigred[2][1] + sigred[3][1];
    double N = 67108864.0;
    sig2s = (float)((Qn - Sn * Sn / N) / (N - 1.0));
  }
  __syncthreads();
  if (t < 64) {
    float Sc = sred[0][t] + sred[1][t] + sred[2][t] + sred[3][t];
    float Qc = qred[0][t] + qred[1][t] + qred[2][t] + qred[3][t];
    float cm = Sc * (1.f / 16384.f);
    float cv = Qc * (1.f / 16384.f) - cm * cm;
    float sc = g1[t] * rsqrtf(cv + sig2s * 1e-5f);
    sc1[t] = sc; cc1[t] = bt1[t] - cm * sc;
  }
  __syncthreads();

  int r0 = blockIdx.x * 64;
  const float* R = ws + WS_R;
  for (int i = t; i < 4096; i += 256) {
    int row = i >> 6, col = i & 63;
    float v = fmaf(R[(size_t)(r0 + row) * 64 + col], sc1[col], cc1[col]);
    h1[row][col] = fmaxf(v, 0.f);
  }
  __syncthreads();
  int row = t & 63, cb = t >> 6;
  float a[8];
  #pragma unroll
  for (int j = 0; j < 8; ++j) a[j] = benc[cb * 8 + j];
  for (int k = 0; k < 64; ++k) {
    float hv = h1[row][k];
    #pragma unroll
    for (int j = 0; j < 8; ++j) a[j] = fmaf(hv, we[k][cb * 8 + j], a[j]);
  }
  float* A2 = ws + WS_A2;
  #pragma unroll
  for (int j = 0; j < 8; ++j) A2[(size_t)(r0 + row) * 32 + cb * 8 + j] = a[j];
  #pragma unroll
  for (int j = 0; j < 8; ++j) {
    float s = a[j], q = a[j] * a[j];
    #pragma unroll
    for (int m = 32; m; m >>= 1) { s += __shfl_xor(s, m); q += __shfl_xor(q, m); }
    if (lane == 0) {
      int c = cb * 8 + j;
      ws[WS_A2PART + blockIdx.x * 64 + c * 2]     = s;
      ws[WS_A2PART + blockIdx.x * 64 + c * 2 + 1] = q;
    }
  }
}

// L4: BN2 finalize + h2 = relu(BN2(a2)), a3 = h2 @ W_dec + b_dec, a3 partials.
__global__ __launch_bounds__(256) void k_layer2(const float* __restrict__ g2, const float* __restrict__ bt2,
                         const float* __restrict__ Wdec, const float* __restrict__ bdec,
                         float* __restrict__ ws){
  __shared__ float h2[64][33];
  __shared__ float wd[32][65];
  __shared__ float sc2[32], cc2[32];
  __shared__ float sred2[8][32], qred2[8][32];
  int t = threadIdx.x, lane = t & 63;
  {
    int col = t & 31, grp = t >> 5;
    float S = 0.f, Q = 0.f;
    for (int b = grp * 32; b < grp * 32 + 32; ++b) {
      S += ws[WS_A2PART + b * 64 + col * 2];
      Q += ws[WS_A2PART + b * 64 + col * 2 + 1];
    }
    sred2[grp][col] = S; qred2[grp][col] = Q;
  }
  for (int i = t; i < 2048; i += 256) wd[i >> 6][i & 63] = Wdec[i];
  __syncthreads();
  if (t < 32) {
    float Sc = 0.f, Qc = 0.f;
    #pragma unroll
    for (int g = 0; g < 8; ++g) { Sc += sred2[g][t]; Qc += qred2[g][t]; }
    float cm = Sc * (1.f / 16384.f);
    float cv = Qc * (1.f / 16384.f) - cm * cm;
    float sc = g2[t] * rsqrtf(cv + 1e-5f);
    sc2[t] = sc; cc2[t] = bt2[t] - cm * sc;
  }
  __syncthreads();
  int r0 = blockIdx.x * 64;
  const float* A2 = ws + WS_A2;
  for (int i = t; i < 2048; i += 256) {
    int row = i >> 5, col = i & 31;
    float v = fmaf(A2[(size_t)(r0 + row) * 32 + col], sc2[col], cc2[col]);
    h2[row][col] = fmaxf(v, 0.f);
  }
  __syncthreads();
  int row = t & 63, cb = t >> 6;
  float a[16];
  #pragma unroll
  for (int j = 0; j < 16; ++j) a[j] = bdec[cb * 16 + j];
  for (int k = 0; k < 32; ++k) {
    float hv = h2[row][k];
    #pragma unroll
    for (int j = 0; j < 16; ++j) a[j] = fmaf(hv, wd[k][cb * 16 + j], a[j]);
  }
  float* A3 = ws + WS_A3;
  #pragma unroll
  for (int j = 0; j < 16; ++j) A3[(size_t)(r0 + row) * 64 + cb * 16 + j] = a[j];
  #pragma unroll
  for (int j = 0; j < 16; ++j) {
    float s = a[j], q = a[j] * a[j];
    #pragma unroll
    for (int m = 32; m; m >>= 1) { s += __shfl_xor(s, m); q += __shfl_xor(q, m); }
    if (lane == 0) {
      int c = cb * 16 + j;
      ws[WS_A3PART + blockIdx.x * 128 + c * 2]     = s;
      ws[WS_A3PART + blockIdx.x * 128 + c * 2 + 1] = q;
    }
  }
}

// L5: reduce a3 partials -> BN3 scale/shift.
__global__ void k_red3(const float* __restrict__ g3, const float* __restrict__ bt3, float* __restrict__ ws){
  __shared__ float red[128];
  int t = threadIdx.x;
  if (t < 128) {
    float s = 0.f;
    for (int b = 0; b < 256; ++b) s += ws[WS_A3PART + b * 128 + t];
    red[t] = s;
  }
  __syncthreads();
  if (t < 64) {
    float S = red[2 * t], Q = red[2 * t + 1];
    float cm = S * (1.f / 16384.f);
    float cv = Q * (1.f / 16384.f) - cm * cm;
    float sc = g3[t] * rsqrtf(cv + 1e-5f);
    ws[WS_SC3 + t] = sc; ws[WS_CC3 + t] = bt3[t] - cm * sc;
  }
}

// L6: heads. h3 = relu(BN3(a3)) in-register; out = act(h3 @ W + b).
// 128 rows x 256 cols per block. RAW barriers (lgkmcnt only) so output stores
// and staged weight loads are NOT drained at each head boundary.
__global__ __launch_bounds__(512) void k_out(const float* __restrict__ bpi, const float* __restrict__ bm,
                      const float* __restrict__ bth, float* __restrict__ out,
                      float* __restrict__ ws){
  __shared__ __align__(16) char WB[256 * 128];   // [256 n][64 k] bf16, XOR-swizzled
  int t = threadIdx.x;
  int bx = blockIdx.x;
  int rb = bx >> 4, cb = bx & 15;
  int r0 = rb * 128, c0 = cb * 256;
  int w = t >> 6, lane = t & 63;
  int u = lane >> 4, li = lane & 15;

  const float* A3 = ws + WS_A3;
  const float* SC = ws + WS_SC3;
  const float* CC = ws + WS_CC3;
  int arow = r0 + w * 16 + li;
  const float4* a3p = (const float4*)(A3 + (size_t)arow * 64);
  bf16x8 aF[2];
  #pragma unroll
  for (int h = 0; h < 2; ++h) {
    float4 v0 = a3p[h * 8 + u * 2];
    float4 v1 = a3p[h * 8 + u * 2 + 1];
    int kb = h * 32 + u * 8;
    u16x8 uu;
    uu[0] = f2bf(fmaxf(fmaf(v0.x, SC[kb+0], CC[kb+0]), 0.f));
    uu[1] = f2bf(fmaxf(fmaf(v0.y, SC[kb+1], CC[kb+1]), 0.f));
    uu[2] = f2bf(fmaxf(fmaf(v0.z, SC[kb+2], CC[kb+2]), 0.f));
    uu[3] = f2bf(fmaxf(fmaf(v0.w, SC[kb+3], CC[kb+3]), 0.f));
    uu[4] = f2bf(fmaxf(fmaf(v1.x, SC[kb+4], CC[kb+4]), 0.f));
    uu[5] = f2bf(fmaxf(fmaf(v1.y, SC[kb+5], CC[kb+5]), 0.f));
    uu[6] = f2bf(fmaxf(fmaf(v1.z, SC[kb+6], CC[kb+6]), 0.f));
    uu[7] = f2bf(fmaxf(fmaf(v1.w, SC[kb+7], CC[kb+7]), 0.f));
    aF[h] = __builtin_bit_cast(bf16x8, uu);
  }

  const unsigned short* wto = (const unsigned short*)(ws + WS_WTO);
  for (int m = 0; m < 3; ++m) {
    BAR_LGKM();               // prior MFMA ds_reads done; stores stay in flight
    const unsigned short* src = wto + (size_t)m * 262144 + (size_t)c0 * 64;
    for (int ch = t; ch < 2048; ch += 512) {
      int n = ch >> 3, kc = ch & 7;
      u16x8 vchunk = *(const u16x8*)(src + n * 64 + kc * 8);
      *(u16x8*)(WB + n * 128 + ((kc ^ (n & 7)) << 4)) = vchunk;
    }
    BAR_LGKM();               // ds_writes visible; no vmcnt drain
    const float* bias = (m == 0) ? bpi : ((m == 1) ? bm : bth);
    float* po = out + (size_t)m * 67108864;
    for (int cg = 0; cg < 16; ++cg) {
      int n = cg * 16 + li;
      bf16x8 bF0 = *(const bf16x8*)(WB + n * 128 + (((0 + u) ^ (n & 7)) << 4));
      bf16x8 bF1 = *(const bf16x8*)(WB + n * 128 + (((4 + u) ^ (n & 7)) << 4));
      f32x4 d = (f32x4){0.f, 0.f, 0.f, 0.f};
      d = __builtin_amdgcn_mfma_f32_16x16x32_bf16(bF0, aF[0], d, 0, 0, 0);
      d = __builtin_amdgcn_mfma_f32_16x16x32_bf16(bF1, aF[1], d, 0, 0, 0);
      int colb = c0 + cg * 16 + u * 4;
      f32x4 bv = *(const f32x4*)(bias + colb);
      f32x4 z;
      #pragma unroll
      for (int r = 0; r < 4; ++r) {
        float zz = d[r] + bv[r];
        z[r] = (m == 0) ? (1.f / (1.f + __expf(-zz))) : __expf(zz);
      }
      *(f32x4*)(po + (size_t)arow * 4096 + colb) = z;
    }
  }
}

extern "C" void kernel_launch(void* const* d_in, const int* in_sizes, int n_in,
                              void* d_out, int out_size, void* d_ws, size_t ws_size,
                              hipStream_t stream) {
  const float* x    = (const float*)d_in[0];
  const float* Win  = (const float*)d_in[1];
  // d_in[2] = b_in: cancels through BN1, unused.
  const float* g1   = (const float*)d_in[3];
  const float* bt1  = (const float*)d_in[4];
  const float* Wenc = (const float*)d_in[5];
  const float* benc = (const float*)d_in[6];
  const float* g2   = (const float*)d_in[7];
  const float* bt2  = (const float*)d_in[8];
  const float* Wdec = (const float*)d_in[9];
  const float* bdec = (const float*)d_in[10];
  const float* g3   = (const float*)d_in[11];
  const float* bt3  = (const float*)d_in[12];
  const float* Wpi  = (const float*)d_in[13];
  const float* bpi  = (const float*)d_in[14];
  const float* Wm   = (const float*)d_in[15];
  const float* bm   = (const float*)d_in[16];
  const float* Wth  = (const float*)d_in[17];
  const float* bth  = (const float*)d_in[18];
  float* ws  = (float*)d_ws;
  float* out = (float*)d_out;

  hipLaunchKernelGGL(k_prep_rowsum, dim3(4352), dim3(256),  0, stream, x, Win, Wpi, Wm, Wth, ws);
  hipLaunchKernelGGL(k_median,      dim3(1),    dim3(1024), 0, stream, ws);
  hipLaunchKernelGGL(k_passB,       dim3(512),  dim3(512),  0, stream, x, ws);
  hipLaunchKernelGGL(k_layer1,      dim3(256),  dim3(256),  0, stream, g1, bt1, Wenc, benc, ws);
  hipLaunchKernelGGL(k_layer2,      dim3(256),  dim3(256),  0, stream, g2, bt2, Wdec, bdec, ws);
  hipLaunchKernelGGL(k_red3,        dim3(1),    dim3(256),  0, stream, g3, bt3, ws);
  hipLaunchKernelGGL(k_out,         dim3(2048), dim3(512),  0, stream, bpi, bm, bth, out, ws);
}

// Round 10
// 373.293 us; speedup vs baseline: 1.5959x; 1.1076x over previous
//
#include <hip/hip_runtime.h>

#define BATCH 16384
#define DIM   4096

typedef __bf16 bf16x8 __attribute__((ext_vector_type(8)));
typedef float  f32x4  __attribute__((ext_vector_type(4)));
typedef unsigned short u16x8 __attribute__((ext_vector_type(8)));
typedef unsigned short u16x4 __attribute__((ext_vector_type(4)));

// Raw barrier: LDS-visibility fence only (skips __syncthreads' vmcnt(0) drain).
#define BAR_LGKM() asm volatile("s_waitcnt lgkmcnt(0)\ns_barrier" ::: "memory")

// ---- workspace layout (float offsets) ----
#define WS_ROWSUM 0         // 16384
#define WS_MED    16384     // 1
#define WS_NPART  16400     // 512*2
#define WS_SC3    17536     // 64
#define WS_CC3    17600     // 64
#define WS_A2PART 18432     // 256*64
#define WS_A3PART 34816     // 256*128
#define WS_CPART  67584     // 512*128 (per-block col sum[64] then sumsq[64])
#define WS_R      133120    // 16384*64 fp32
#define WS_A2     1181696   // 16384*32 fp32
#define WS_A3     1705984   // 16384*64 fp32
#define WS_WTIN   2754560   // 64*4096 bf16 (as ushort)
#define WS_WTO    2885632   // 3 * 4096*64 bf16

__device__ __forceinline__ unsigned short f2bf(float f){
  union { float f; unsigned u; } v; v.f = f;
  unsigned r = v.u + 0x7FFFu + ((v.u >> 16) & 1u);
  return (unsigned short)(r >> 16);
}

// L0: weight transpose/bf16 prep via LDS (blocks 0..255) + row sums of x.
__global__ __launch_bounds__(256) void k_prep_rowsum(
    const float* __restrict__ x, const float* __restrict__ Win,
    const float* __restrict__ Wpi, const float* __restrict__ Wm,
    const float* __restrict__ Wth, float* __restrict__ ws){
  int b = blockIdx.x, t = threadIdx.x;
  if (b < 256) {
    __shared__ unsigned short tile[64][72];
    if (b < 64) {
      int k0 = b * 64;
      int n = t & 63, kb = t >> 6;
      #pragma unroll
      for (int i = 0; i < 16; ++i) {
        int kk = kb * 16 + i;
        tile[n][kk] = f2bf(Win[(size_t)(k0 + kk) * 64 + n]);
      }
      __syncthreads();
      unsigned short* wtin = (unsigned short*)(ws + WS_WTIN);
      int c = t & 7;
      #pragma unroll
      for (int p = 0; p < 2; ++p) {
        int nn = (t >> 3) + p * 32;
        u16x8 v = *(const u16x8*)&tile[nn][c * 8];
        *(u16x8*)(wtin + (size_t)nn * 4096 + k0 + c * 8) = v;
      }
    } else {
      int bm = (b - 64) >> 6;
      int n0 = ((b - 64) & 63) * 64;
      const float* W = (bm == 0) ? Wpi : ((bm == 1) ? Wm : Wth);
      int nn = t & 63, kb = t >> 6;
      #pragma unroll
      for (int i = 0; i < 16; ++i) {
        int k = kb * 16 + i;
        tile[nn][k] = f2bf(W[(size_t)k * 4096 + n0 + nn]);
      }
      __syncthreads();
      unsigned short* wto = (unsigned short*)(ws + WS_WTO);
      int c = t & 7;
      #pragma unroll
      for (int p = 0; p < 2; ++p) {
        int nn2 = (t >> 3) + p * 32;
        u16x8 v = *(const u16x8*)&tile[nn2][c * 8];
        *(u16x8*)(wto + (size_t)bm * 262144 + (size_t)(n0 + nn2) * 64 + c * 8) = v;
      }
    }
  } else {
    int w = t >> 6, lane = t & 63;
    int row = (b - 256) * 4 + w;
    const float4* xr = (const float4*)(x + (size_t)row * DIM);
    float s = 0.f;
    #pragma unroll
    for (int i = 0; i < 16; ++i) {
      float4 v = xr[lane + 64 * i];
      s += (v.x + v.y) + (v.z + v.w);
    }
    #pragma unroll
    for (int m = 32; m; m >>= 1) s += __shfl_xor(s, m);
    if (lane == 0) ws[WS_ROWSUM + row] = s;
  }
}

// L1: exact lower median via 3-pass MSD radix (bits 12/12/8).
__global__ __launch_bounds__(1024) void k_median(float* __restrict__ ws){
  __shared__ unsigned keys[16384];
  __shared__ int hist[4096];
  __shared__ int scanbuf[1024];
  __shared__ int selBin, selRank;
  int t = threadIdx.x, lane = t & 63;

  for (int i = t; i < 16384; i += 1024) keys[i] = __float_as_uint(ws[WS_ROWSUM + i]);
  for (int i = t; i < 4096; i += 1024) hist[i] = 0;
  __syncthreads();

  auto scanFind = [&](int target) {
    int s = hist[4*t] + hist[4*t+1] + hist[4*t+2] + hist[4*t+3];
    scanbuf[t] = s;
    __syncthreads();
    for (int off = 1; off < 1024; off <<= 1) {
      int v = scanbuf[t];
      int a = (t >= off) ? scanbuf[t - off] : 0;
      __syncthreads();
      scanbuf[t] = v + a;
      __syncthreads();
    }
    int acc = scanbuf[t] - s;
    #pragma unroll
    for (int j = 0; j < 4; ++j) {
      int c = hist[4*t + j];
      if (acc <= target && target < acc + c) { selBin = 4*t + j; selRank = target - acc; }
      acc += c;
    }
    __syncthreads();
  };

  for (int i = t; i < 16384; i += 1024) {
    unsigned key = keys[i] >> 20;
    unsigned long long unclaimed = __ballot(1);
    int cnt = 0; bool leader = false;
    while (true) {
      int src = (int)(__ffsll((unsigned long long)unclaimed)) - 1;
      unsigned k0 = (unsigned)__shfl((int)key, src);
      unsigned long long eq = __ballot(k0 == key);
      if (k0 == key) { leader = (lane == src); cnt = (int)__popcll(eq); break; }
      unclaimed &= ~eq;
    }
    if (leader) atomicAdd(&hist[key], cnt);
  }
  __syncthreads();
  scanFind(8191);
  unsigned B1 = (unsigned)selBin; int r1 = selRank;
  __syncthreads();
  for (int i = t; i < 4096; i += 1024) hist[i] = 0;
  __syncthreads();
  for (int i = t; i < 16384; i += 1024) {
    unsigned u = keys[i];
    if ((u >> 20) == B1) atomicAdd(&hist[(u >> 8) & 0xFFF], 1);
  }
  __syncthreads();
  scanFind(r1);
  unsigned B2 = (unsigned)selBin; int r2 = selRank;
  __syncthreads();
  for (int i = t; i < 4096; i += 1024) hist[i] = 0;
  __syncthreads();
  unsigned hi24 = (B1 << 12) | B2;
  for (int i = t; i < 16384; i += 1024) {
    unsigned u = keys[i];
    if ((u >> 8) == hi24) atomicAdd(&hist[u & 0xFF], 1);
  }
  __syncthreads();
  scanFind(r2);
  if (t == 0) {
    unsigned bits = (B1 << 20) | (B2 << 8) | (unsigned)selBin;
    ws[WS_MED] = __uint_as_float(bits);
  }
}

// L2: fused norm + R = norm @ W_in + stats. (r9-verified: 4-deep prefetch,
// raw lgkm barriers, reverse row order.)
__global__ __launch_bounds__(512) void k_passB(const float* __restrict__ x, float* __restrict__ ws){
  __shared__ __align__(16) char Ab[2 * 4096];
  __shared__ __align__(16) char Bb[2 * 8192];
  __shared__ float ainv_s[32];
  __shared__ float redn[8][2];
  __shared__ float cpart[2][64], cqpart[2][64];

  const unsigned short* wtin = (const unsigned short*)(ws + WS_WTIN);
  int tid = threadIdx.x;
  int r0 = (511 - (int)blockIdx.x) * 32;
  float med = ws[WS_MED];
  if (tid < 32) ainv_s[tid] = med / ws[WS_ROWSUM + r0 + tid];
  __syncthreads();

  int w = tid >> 6, lane = tid & 63;
  int li = lane & 15, u = lane >> 4;
  int wrb = (w & 1) * 16;
  int wc  = (w >> 1) * 16;

  int xrow = tid >> 4;
  int xcol0 = (tid & 15) * 4;
  int wn = tid >> 3, wkc = tid & 7;
  float ainv = ainv_s[xrow];

  f32x4 acc = (f32x4){0.f, 0.f, 0.f, 0.f};
  float nsum = 0.f, nsq = 0.f;
  float4 xa0, xa1, xa2, xa3; u16x8 wv0, wv1, wv2, wv3;

  auto LOADT = [&](int tt, float4& xv, u16x8& wq){
    int coff = tt * 64;
    xv = *(const float4*)(x + (size_t)(r0 + xrow) * DIM + coff + xcol0);
    wq = *(const u16x8*)(wtin + (size_t)wn * DIM + coff + wkc * 8);
  };
  auto WRITET = [&](int buf, const float4& xv, const u16x8& wq){
    float n0 = __logf(fmaf(xv.x, ainv, 1.f));
    float n1 = __logf(fmaf(xv.y, ainv, 1.f));
    float n2 = __logf(fmaf(xv.z, ainv, 1.f));
    float n3 = __logf(fmaf(xv.w, ainv, 1.f));
    nsum += (n0 + n1) + (n2 + n3);
    nsq  += (n0*n0 + n1*n1) + (n2*n2 + n3*n3);
    u16x4 p = { f2bf(n0), f2bf(n1), f2bf(n2), f2bf(n3) };
    int c = xcol0 >> 3, sub = (xcol0 >> 2) & 1;
    *(u16x4*)(Ab + buf * 4096 + xrow * 128 + ((c ^ (xrow & 7)) << 4) + sub * 8) = p;
    *(u16x8*)(Bb + buf * 8192 + wn * 128 + ((wkc ^ (wn & 7)) << 4)) = wq;
  };
  int arow = wrb + li, brow = wc + li;
  auto DOMFMA = [&](int p){
    const char* Au = Ab + p * 4096;
    const char* Bu = Bb + p * 8192;
    #pragma unroll
    for (int kk = 0; kk < 2; ++kk) {
      bf16x8 aF = *(const bf16x8*)(Au + arow * 128 + (((kk * 4 + u) ^ (arow & 7)) << 4));
      bf16x8 bF = *(const bf16x8*)(Bu + brow * 128 + (((kk * 4 + u) ^ (brow & 7)) << 4));
      acc = __builtin_amdgcn_mfma_f32_16x16x32_bf16(bF, aF, acc, 0, 0, 0);
    }
  };

  LOADT(0, xa0, wv0);
  LOADT(1, xa1, wv1);
  LOADT(2, xa2, wv2);
  WRITET(0, xa0, wv0);
  BAR_LGKM();
  for (int t = 0; t < 64; t += 4) {
    if (t + 3 < 64) LOADT(t + 3, xa3, wv3);
    WRITET(1, xa1, wv1);
    DOMFMA(0);
    BAR_LGKM();
    if (t + 4 < 64) LOADT(t + 4, xa0, wv0);
    WRITET(0, xa2, wv2);
    DOMFMA(1);
    BAR_LGKM();
    if (t + 5 < 64) LOADT(t + 5, xa1, wv1);
    if (t + 3 < 64) WRITET(1, xa3, wv3);
    DOMFMA(0);
    BAR_LGKM();
    if (t + 6 < 64) LOADT(t + 6, xa2, wv2);
    if (t + 4 < 64) WRITET(0, xa0, wv0);
    DOMFMA(1);
    BAR_LGKM();
  }

  float* R = ws + WS_R;
  *(f32x4*)(R + (size_t)(r0 + wrb + li) * 64 + wc + u * 4) = acc;

  float s0 = acc[0], s1 = acc[1], s2 = acc[2], s3 = acc[3];
  float q0 = acc[0]*acc[0], q1 = acc[1]*acc[1], q2 = acc[2]*acc[2], q3 = acc[3]*acc[3];
  #pragma unroll
  for (int m = 1; m < 16; m <<= 1) {
    s0 += __shfl_xor(s0, m); s1 += __shfl_xor(s1, m);
    s2 += __shfl_xor(s2, m); s3 += __shfl_xor(s3, m);
    q0 += __shfl_xor(q0, m); q1 += __shfl_xor(q1, m);
    q2 += __shfl_xor(q2, m); q3 += __shfl_xor(q3, m);
  }
  if (li == 0) {
    int cb = wc + u * 4;
    cpart[w & 1][cb + 0] = s0; cpart[w & 1][cb + 1] = s1;
    cpart[w & 1][cb + 2] = s2; cpart[w & 1][cb + 3] = s3;
    cqpart[w & 1][cb + 0] = q0; cqpart[w & 1][cb + 1] = q1;
    cqpart[w & 1][cb + 2] = q2; cqpart[w & 1][cb + 3] = q3;
  }
  #pragma unroll
  for (int m = 32; m; m >>= 1) { nsum += __shfl_xor(nsum, m); nsq += __shfl_xor(nsq, m); }
  if (lane == 0) { redn[w][0] = nsum; redn[w][1] = nsq; }
  BAR_LGKM();
  if (tid < 64) {
    ws[WS_CPART + blockIdx.x * 128 + tid]      = cpart[0][tid] + cpart[1][tid];
    ws[WS_CPART + blockIdx.x * 128 + 64 + tid] = cqpart[0][tid] + cqpart[1][tid];
  }
  if (tid == 0) {
    float S = 0.f, Q = 0.f;
    for (int i = 0; i < 8; ++i) { S += redn[i][0]; Q += redn[i][1]; }
    ws[WS_NPART + blockIdx.x * 2]     = S;
    ws[WS_NPART + blockIdx.x * 2 + 1] = Q;
  }
}

// L3: BN1 finalize + h1 = relu(BN1(R)), a2 = h1 @ W_enc + b_enc, a2 partials.
__global__ __launch_bounds__(256) void k_layer1(const float* __restrict__ g1, const float* __restrict__ bt1,
                         const float* __restrict__ Wenc, const float* __restrict__ benc,
                         float* __restrict__ ws){
  __shared__ float sc1[64], cc1[64];
  __shared__ float h1[64][65];
  __shared__ float we[64][33];
  __shared__ float sred[4][64], qred[4][64];
  __shared__ float sigred[4][2];
  __shared__ float sig2s;
  int t = threadIdx.x, lane = t & 63, w4 = t >> 6;

  {
    float s = 0.f, q = 0.f;
    for (int b = t; b < 512; b += 256) { s += ws[WS_NPART + b * 2]; q += ws[WS_NPART + b * 2 + 1]; }
    #pragma unroll
    for (int m = 32; m; m >>= 1) { s += __shfl_xor(s, m); q += __shfl_xor(q, m); }
    if (lane == 0) { sigred[w4][0] = s; sigred[w4][1] = q; }
  }
  {
    int col = t & 63, grp = t >> 6;
    float S = 0.f, Q = 0.f;
    for (int b = grp * 128; b < grp * 128 + 128; ++b) {
      S += ws[WS_CPART + b * 128 + col];
      Q += ws[WS_CPART + b * 128 + 64 + col];
    }
    sred[grp][col] = S; qred[grp][col] = Q;
  }
  for (int i = t; i < 2048; i += 256) we[i >> 5][i & 31] = Wenc[i];
  __syncthreads();
  if (t == 0) {
    double Sn = (double)sigred[0][0] + sigred[1][0] + sigred[2][0] + sigred[3][0];
    double Qn = (double)sigred[0][1] + sigred[1][1] + sigred[2][1] + sigred[3][1];
    double N = 67108864.0;
    sig2s = (float)((Qn - Sn * Sn / N) / (N - 1.0));
  }
  __syncthreads();
  if (t < 64) {
    float Sc = sred[0][t] + sred[1][t] + sred[2][t] + sred[3][t];
    float Qc = qred[0][t] + qred[1][t] + qred[2][t] + qred[3][t];
    float cm = Sc * (1.f / 16384.f);
    float cv = Qc * (1.f / 16384.f) - cm * cm;
    float sc = g1[t] * rsqrtf(cv + sig2s * 1e-5f);
    sc1[t] = sc; cc1[t] = bt1[t] - cm * sc;
  }
  __syncthreads();

  int r0 = blockIdx.x * 64;
  const float* R = ws + WS_R;
  for (int i = t; i < 4096; i += 256) {
    int row = i >> 6, col = i & 63;
    float v = fmaf(R[(size_t)(r0 + row) * 64 + col], sc1[col], cc1[col]);
    h1[row][col] = fmaxf(v, 0.f);
  }
  __syncthreads();
  int row = t & 63, cb = t >> 6;
  float a[8];
  #pragma unroll
  for (int j = 0; j < 8; ++j) a[j] = benc[cb * 8 + j];
  for (int k = 0; k < 64; ++k) {
    float hv = h1[row][k];
    #pragma unroll
    for (int j = 0; j < 8; ++j) a[j] = fmaf(hv, we[k][cb * 8 + j], a[j]);
  }
  float* A2 = ws + WS_A2;
  #pragma unroll
  for (int j = 0; j < 8; ++j) A2[(size_t)(r0 + row) * 32 + cb * 8 + j] = a[j];
  #pragma unroll
  for (int j = 0; j < 8; ++j) {
    float s = a[j], q = a[j] * a[j];
    #pragma unroll
    for (int m = 32; m; m >>= 1) { s += __shfl_xor(s, m); q += __shfl_xor(q, m); }
    if (lane == 0) {
      int c = cb * 8 + j;
      ws[WS_A2PART + blockIdx.x * 64 + c * 2]     = s;
      ws[WS_A2PART + blockIdx.x * 64 + c * 2 + 1] = q;
    }
  }
}

// L4: BN2 finalize + h2 = relu(BN2(a2)), a3 = h2 @ W_dec + b_dec, a3 partials.
__global__ __launch_bounds__(256) void k_layer2(const float* __restrict__ g2, const float* __restrict__ bt2,
                         const float* __restrict__ Wdec, const float* __restrict__ bdec,
                         float* __restrict__ ws){
  __shared__ float h2[64][33];
  __shared__ float wd[32][65];
  __shared__ float sc2[32], cc2[32];
  __shared__ float sred2[8][32], qred2[8][32];
  int t = threadIdx.x, lane = t & 63;
  {
    int col = t & 31, grp = t >> 5;
    float S = 0.f, Q = 0.f;
    for (int b = grp * 32; b < grp * 32 + 32; ++b) {
      S += ws[WS_A2PART + b * 64 + col * 2];
      Q += ws[WS_A2PART + b * 64 + col * 2 + 1];
    }
    sred2[grp][col] = S; qred2[grp][col] = Q;
  }
  for (int i = t; i < 2048; i += 256) wd[i >> 6][i & 63] = Wdec[i];
  __syncthreads();
  if (t < 32) {
    float Sc = 0.f, Qc = 0.f;
    #pragma unroll
    for (int g = 0; g < 8; ++g) { Sc += sred2[g][t]; Qc += qred2[g][t]; }
    float cm = Sc * (1.f / 16384.f);
    float cv = Qc * (1.f / 16384.f) - cm * cm;
    float sc = g2[t] * rsqrtf(cv + 1e-5f);
    sc2[t] = sc; cc2[t] = bt2[t] - cm * sc;
  }
  __syncthreads();
  int r0 = blockIdx.x * 64;
  const float* A2 = ws + WS_A2;
  for (int i = t; i < 2048; i += 256) {
    int row = i >> 5, col = i & 31;
    float v = fmaf(A2[(size_t)(r0 + row) * 32 + col], sc2[col], cc2[col]);
    h2[row][col] = fmaxf(v, 0.f);
  }
  __syncthreads();
  int row = t & 63, cb = t >> 6;
  float a[16];
  #pragma unroll
  for (int j = 0; j < 16; ++j) a[j] = bdec[cb * 16 + j];
  for (int k = 0; k < 32; ++k) {
    float hv = h2[row][k];
    #pragma unroll
    for (int j = 0; j < 16; ++j) a[j] = fmaf(hv, wd[k][cb * 16 + j], a[j]);
  }
  float* A3 = ws + WS_A3;
  #pragma unroll
  for (int j = 0; j < 16; ++j) A3[(size_t)(r0 + row) * 64 + cb * 16 + j] = a[j];
  #pragma unroll
  for (int j = 0; j < 16; ++j) {
    float s = a[j], q = a[j] * a[j];
    #pragma unroll
    for (int m = 32; m; m >>= 1) { s += __shfl_xor(s, m); q += __shfl_xor(q, m); }
    if (lane == 0) {
      int c = cb * 16 + j;
      ws[WS_A3PART + blockIdx.x * 128 + c * 2]     = s;
      ws[WS_A3PART + blockIdx.x * 128 + c * 2 + 1] = q;
    }
  }
}

// L5: reduce a3 partials -> BN3 scale/shift.
__global__ void k_red3(const float* __restrict__ g3, const float* __restrict__ bt3, float* __restrict__ ws){
  __shared__ float red[128];
  int t = threadIdx.x;
  if (t < 128) {
    float s = 0.f;
    for (int b = 0; b < 256; ++b) s += ws[WS_A3PART + b * 128 + t];
    red[t] = s;
  }
  __syncthreads();
  if (t < 64) {
    float S = red[2 * t], Q = red[2 * t + 1];
    float cm = S * (1.f / 16384.f);
    float cv = Q * (1.f / 16384.f) - cm * cm;
    float sc = g3[t] * rsqrtf(cv + 1e-5f);
    ws[WS_SC3 + t] = sc; ws[WS_CC3 + t] = bt3[t] - cm * sc;
  }
}

// L6 REDESIGN: zero-barrier, zero-LDS heads kernel.
// Grid 256 = 16 row-slabs x 16 col-blocks; 512 threads; 1024 rows/block.
// Per head, per cg-half: W fragments loaded ONCE into registers (64 VGPR,
// L2-hot, OFF the MFMA chain), then 8 row-tiles streamed with 1-tile-ahead
// A3 prefetch. Stores are fire-and-forget; no syncs anywhere.
__global__ __launch_bounds__(512) void k_out(const float* __restrict__ bpi, const float* __restrict__ bm,
                      const float* __restrict__ bth, float* __restrict__ out,
                      float* __restrict__ ws){
  int t = threadIdx.x;
  int bx = blockIdx.x;
  int rs = bx >> 4, cb = bx & 15;
  int r0 = rs * 1024, c0 = cb * 256;
  int w = t >> 6, lane = t & 63;
  int u = lane >> 4, li = lane & 15;

  const float* A3 = ws + WS_A3;
  const float* SC = ws + WS_SC3;
  const float* CC = ws + WS_CC3;
  // per-thread BN3 constants: k in {u*8..u*8+7} and {32+u*8..32+u*8+7}
  float4 sA0 = *(const float4*)(SC + u * 8);
  float4 sA1 = *(const float4*)(SC + u * 8 + 4);
  float4 sB0 = *(const float4*)(SC + 32 + u * 8);
  float4 sB1 = *(const float4*)(SC + 32 + u * 8 + 4);
  float4 cA0 = *(const float4*)(CC + u * 8);
  float4 cA1 = *(const float4*)(CC + u * 8 + 4);
  float4 cB0 = *(const float4*)(CC + 32 + u * 8);
  float4 cB1 = *(const float4*)(CC + 32 + u * 8 + 4);

  int rowbase = r0 + w * 128 + li;
  const unsigned short* wto = (const unsigned short*)(ws + WS_WTO);

  for (int m = 0; m < 3; ++m) {
    const unsigned short* src = wto + (size_t)m * 262144 + (size_t)c0 * 64;
    const float* bias = (m == 0) ? bpi : ((m == 1) ? bm : bth);
    float* po = out + (size_t)m * 67108864;
    #pragma unroll
    for (int half = 0; half < 2; ++half) {
      // load 8 cg's worth of B fragments into registers (statically indexed)
      bf16x8 bF0[8], bF1[8];
      #pragma unroll
      for (int cg = 0; cg < 8; ++cg) {
        int n = (half * 8 + cg) * 16 + li;
        bF0[cg] = *(const bf16x8*)(src + (size_t)n * 64 + u * 8);
        bF1[cg] = *(const bf16x8*)(src + (size_t)n * 64 + 32 + u * 8);
      }
      // prefetch tile 0's A3
      float4 p0, p1, p2, p3;
      {
        const float4* a3p = (const float4*)(A3 + (size_t)rowbase * 64);
        p0 = a3p[u * 2]; p1 = a3p[u * 2 + 1]; p2 = a3p[8 + u * 2]; p3 = a3p[8 + u * 2 + 1];
      }
      for (int tile = 0; tile < 8; ++tile) {
        float4 n0, n1, n2, n3;
        if (tile < 7) {
          const float4* a3p = (const float4*)(A3 + (size_t)(rowbase + (tile + 1) * 16) * 64);
          n0 = a3p[u * 2]; n1 = a3p[u * 2 + 1]; n2 = a3p[8 + u * 2]; n3 = a3p[8 + u * 2 + 1];
        }
        // build A fragments (BN3 + relu + bf16)
        u16x8 uu0, uu1;
        uu0[0] = f2bf(fmaxf(fmaf(p0.x, sA0.x, cA0.x), 0.f));
        uu0[1] = f2bf(fmaxf(fmaf(p0.y, sA0.y, cA0.y), 0.f));
        uu0[2] = f2bf(fmaxf(fmaf(p0.z, sA0.z, cA0.z), 0.f));
        uu0[3] = f2bf(fmaxf(fmaf(p0.w, sA0.w, cA0.w), 0.f));
        uu0[4] = f2bf(fmaxf(fmaf(p1.x, sA1.x, cA1.x), 0.f));
        uu0[5] = f2bf(fmaxf(fmaf(p1.y, sA1.y, cA1.y), 0.f));
        uu0[6] = f2bf(fmaxf(fmaf(p1.z, sA1.z, cA1.z), 0.f));
        uu0[7] = f2bf(fmaxf(fmaf(p1.w, sA1.w, cA1.w), 0.f));
        uu1[0] = f2bf(fmaxf(fmaf(p2.x, sB0.x, cB0.x), 0.f));
        uu1[1] = f2bf(fmaxf(fmaf(p2.y, sB0.y, cB0.y), 0.f));
        uu1[2] = f2bf(fmaxf(fmaf(p2.z, sB0.z, cB0.z), 0.f));
        uu1[3] = f2bf(fmaxf(fmaf(p2.w, sB0.w, cB0.w), 0.f));
        uu1[4] = f2bf(fmaxf(fmaf(p3.x, sB1.x, cB1.x), 0.f));
        uu1[5] = f2bf(fmaxf(fmaf(p3.y, sB1.y, cB1.y), 0.f));
        uu1[6] = f2bf(fmaxf(fmaf(p3.z, sB1.z, cB1.z), 0.f));
        uu1[7] = f2bf(fmaxf(fmaf(p3.w, sB1.w, cB1.w), 0.f));
        bf16x8 aF0 = __builtin_bit_cast(bf16x8, uu0);
        bf16x8 aF1 = __builtin_bit_cast(bf16x8, uu1);
        int arow = rowbase + tile * 16;
        #pragma unroll
        for (int cg = 0; cg < 8; ++cg) {
          f32x4 d = (f32x4){0.f, 0.f, 0.f, 0.f};
          d = __builtin_amdgcn_mfma_f32_16x16x32_bf16(bF0[cg], aF0, d, 0, 0, 0);
          d = __builtin_amdgcn_mfma_f32_16x16x32_bf16(bF1[cg], aF1, d, 0, 0, 0);
          int colb = c0 + (half * 8 + cg) * 16 + u * 4;
          f32x4 bv = *(const f32x4*)(bias + colb);
          f32x4 z;
          #pragma unroll
          for (int r = 0; r < 4; ++r) {
            float zz = d[r] + bv[r];
            z[r] = (m == 0) ? (1.f / (1.f + __expf(-zz))) : __expf(zz);
          }
          *(f32x4*)(po + (size_t)arow * 4096 + colb) = z;
        }
        p0 = n0; p1 = n1; p2 = n2; p3 = n3;
      }
    }
  }
}

extern "C" void kernel_launch(void* const* d_in, const int* in_sizes, int n_in,
                              void* d_out, int out_size, void* d_ws, size_t ws_size,
                              hipStream_t stream) {
  const float* x    = (const float*)d_in[0];
  const float* Win  = (const float*)d_in[1];
  // d_in[2] = b_in: cancels through BN1, unused.
  const float* g1   = (const float*)d_in[3];
  const float* bt1  = (const float*)d_in[4];
  const float* Wenc = (const float*)d_in[5];
  const float* benc = (const float*)d_in[6];
  const float* g2   = (const float*)d_in[7];
  const float* bt2  = (const float*)d_in[8];
  const float* Wdec = (const float*)d_in[9];
  const float* bdec = (const float*)d_in[10];
  const float* g3   = (const float*)d_in[11];
  const float* bt3  = (const float*)d_in[12];
  const float* Wpi  = (const float*)d_in[13];
  const float* bpi  = (const float*)d_in[14];
  const float* Wm   = (const float*)d_in[15];
  const float* bm   = (const float*)d_in[16];
  const float* Wth  = (const float*)d_in[17];
  const float* bth  = (const float*)d_in[18];
  float* ws  = (float*)d_ws;
  float* out = (float*)d_out;

  hipLaunchKernelGGL(k_prep_rowsum, dim3(4352), dim3(256),  0, stream, x, Win, Wpi, Wm, Wth, ws);
  hipLaunchKernelGGL(k_median,      dim3(1),    dim3(1024), 0, stream, ws);
  hipLaunchKernelGGL(k_passB,       dim3(512),  dim3(512),  0, stream, x, ws);
  hipLaunchKernelGGL(k_layer1,      dim3(256),  dim3(256),  0, stream, g1, bt1, Wenc, benc, ws);
  hipLaunchKernelGGL(k_layer2,      dim3(256),  dim3(256),  0, stream, g2, bt2, Wdec, bdec, ws);
  hipLaunchKernelGGL(k_red3,        dim3(1),    dim3(256),  0, stream, g3, bt3, ws);
  hipLaunchKernelGGL(k_out,         dim3(256),  dim3(512),  0, stream, bpi, bm, bth, out, ws);
}